// Round 8
// baseline (846.118 us; speedup 1.0000x reference)
//
#include <hip/hip_runtime.h>
#include <stdint.h>

// ---------------------------------------------------------------------------
// BatchWhiten: out = x @ inv_sqrtm(max(0.1*running + 0.9*(x^T x)/N, 1e-5))
// x: [262144, 512] fp32, running: [512,512] fp32, out: [262144,512] fp32
// ---------------------------------------------------------------------------

#define N_ROWS 262144
#define D 512
#define NS_ITERS 3  // 1 simplified (Z0=I) + 1 full + 1 final Z-only (fused)
#define CK_CHUNKS 128
#define CK_ROWS (N_ROWS / CK_CHUNKS)  // 2048
#define BKC 32
#define CK_STEPS (CK_ROWS / BKC)      // 64

typedef float f32x4 __attribute__((ext_vector_type(4)));
typedef short s16x8 __attribute__((ext_vector_type(8)));
typedef short s16x4 __attribute__((ext_vector_type(4)));
typedef __bf16 bf16x8 __attribute__((ext_vector_type(8)));

static __device__ __forceinline__ unsigned short f2bf(float f) {
  unsigned u = __float_as_uint(f);
  u += 0x7FFFu + ((u >> 16) & 1u);  // RNE
  return (unsigned short)(u >> 16);
}

static __device__ __forceinline__ f32x4 mfma16(s16x8 a, s16x8 b, f32x4 c) {
  return __builtin_amdgcn_mfma_f32_16x16x32_bf16(
      __builtin_bit_cast(bf16x8, a), __builtin_bit_cast(bf16x8, b), c, 0, 0, 0);
}

// async global->LDS, 16B per lane; LDS dest = wave-uniform base + lane*16
static __device__ __forceinline__ void gld_lds16(const void* g, void* l) {
  __builtin_amdgcn_global_load_lds(
      (const __attribute__((address_space(1))) void*)g,
      (__attribute__((address_space(3))) void*)l, 16, 0, 0);
}

#define SWZ4(c) (((c) ^ ((c) >> 2)) & 3)
#define SWZ8(c) (((c) ^ ((c) >> 3)) & 7)

// ---------------------------------------------------------------------------
// Kernel 1: Cpart[xcd] += x^T x (split-K, bf16 MFMA, upper tiles mb<=nb).
// grid 1280 (10 tiles x 128 chunks), BK=32, REGISTER double-buffer: step
// s+1's global loads are issued right after the barrier so their ~900cy HBM
// latency hides under MFMA + barriers + next convert (T14 async-STAGE).
// __launch_bounds__(256,4) pins VGPR<=128 -> 16 waves/CU.
// XCD-swizzled: a chunk's 10 works at hw-stride-8 share one XCD's L2.
// xb16 dump balanced: each tile's 4 stagers (ranks 0..3) dump the kh==rank
// 8-row quarter per step; dump stores nontemporal.
// ---------------------------------------------------------------------------
__global__ __launch_bounds__(256, 4) void covar_k(const float* __restrict__ x,
                                                  float* __restrict__ Cpart,
                                                  short* __restrict__ xb16) {
  __shared__ short ldsA[128 * 32];
  __shared__ short ldsB[128 * 32];

  // bijective XCD swizzle: 1280 works = 8 XCDs x 160
  const int hw = blockIdx.x;
  const int work = (hw & 7) * 160 + (hw >> 3);
  int t = work % 10, mb = 0, rl = 4;
  while (t >= rl) { t -= rl; ++mb; --rl; }
  const int nb = mb + t;
  const int chunk = work / 10;
  float* C = Cpart + (size_t)(hw & 7) * (D * D);

  const int tid = threadIdx.x;
  const int c2 = (tid & 63) * 2;  // columns c2, c2+1 of the tile
  const int kh = tid >> 6;        // 0..3: rows [8kh, 8kh+8) of the step

  const int lane = tid & 63;
  const int wave = tid >> 6;
  const int wr = wave >> 1, wc = wave & 1;
  const int l15 = lane & 15, g = lane >> 4;

  const bool offd = (nb != mb);
  const bool haveDump = (xb16 != nullptr);
  const int rankA = nb - mb;        // 0 for diagonal works
  const int rankB = 4 - (nb - mb);  // only meaningful off-diagonal
  const bool dumpA = haveDump && (kh == rankA);
  const bool dumpB = haveDump && offd && (kh == rankB);
  uint32_t* xw = (uint32_t*)xb16;

  f32x4 acc[4][4];
#pragma unroll
  for (int i = 0; i < 4; ++i)
#pragma unroll
    for (int j = 0; j < 4; ++j) acc[i][j] = f32x4{0.f, 0.f, 0.f, 0.f};

  const size_t kbase0 = (size_t)chunk * CK_ROWS;

  // register prefetch buffers (step double-buffer lives in regs)
  float2 bufM[8], bufN[8];
  {
    const float* srcM = x + (kbase0 + kh * 8) * D + mb * 128 + c2;
#pragma unroll
    for (int q = 0; q < 8; ++q) bufM[q] = *(const float2*)(srcM + (size_t)q * D);
    if (offd) {
      const float* srcN = x + (kbase0 + kh * 8) * D + nb * 128 + c2;
#pragma unroll
      for (int q = 0; q < 8; ++q) bufN[q] = *(const float2*)(srcN + (size_t)q * D);
    }
  }

  for (int st = 0; st < CK_STEPS; ++st) {
    const size_t k0 = kbase0 + (size_t)st * BKC;

    // convert current step's registers to bf16 (loads already landed)
    s16x8 pM0, pM1, pN0, pN1;
#pragma unroll
    for (int q = 0; q < 8; ++q) {
      pM0[q] = (short)f2bf(bufM[q].x);
      pM1[q] = (short)f2bf(bufM[q].y);
    }
    if (offd) {
#pragma unroll
      for (int q = 0; q < 8; ++q) {
        pN0[q] = (short)f2bf(bufN[q].x);
        pN1[q] = (short)f2bf(bufN[q].y);
      }
    }

    __syncthreads();  // MFMA of st-1 finished reading LDS
    *(s16x8*)(ldsA + c2 * 32 + ((kh ^ SWZ4(c2)) << 3)) = pM0;
    *(s16x8*)(ldsA + (c2 + 1) * 32 + ((kh ^ SWZ4(c2 + 1)) << 3)) = pM1;
    if (offd) {
      *(s16x8*)(ldsB + c2 * 32 + ((kh ^ SWZ4(c2)) << 3)) = pN0;
      *(s16x8*)(ldsB + (c2 + 1) * 32 + ((kh ^ SWZ4(c2 + 1)) << 3)) = pN1;
    }
    if (dumpA) {
#pragma unroll
      for (int q = 0; q < 8; ++q) {
        const uint32_t u =
            (uint32_t)(uint16_t)pM0[q] | ((uint32_t)(uint16_t)pM1[q] << 16);
        __builtin_nontemporal_store(
            u, &xw[(k0 + kh * 8 + q) * 256 + mb * 64 + (c2 >> 1)]);
      }
    }
    if (dumpB) {
#pragma unroll
      for (int q = 0; q < 8; ++q) {
        const uint32_t u =
            (uint32_t)(uint16_t)pN0[q] | ((uint32_t)(uint16_t)pN1[q] << 16);
        __builtin_nontemporal_store(
            u, &xw[(k0 + kh * 8 + q) * 256 + nb * 64 + (c2 >> 1)]);
      }
    }
    __syncthreads();

    // issue NEXT step's loads now — latency hides under MFMA + barriers
    if (st + 1 < CK_STEPS) {
      const float* srcM = x + (k0 + BKC + kh * 8) * D + mb * 128 + c2;
#pragma unroll
      for (int q = 0; q < 8; ++q)
        bufM[q] = *(const float2*)(srcM + (size_t)q * D);
      if (offd) {
        const float* srcN = x + (k0 + BKC + kh * 8) * D + nb * 128 + c2;
#pragma unroll
        for (int q = 0; q < 8; ++q)
          bufN[q] = *(const float2*)(srcN + (size_t)q * D);
      }
    }

    // MFMA on current LDS tiles
    const short* Bp = offd ? ldsB : ldsA;
    s16x8 af[4], bfv[4];
#pragma unroll
    for (int mi = 0; mi < 4; ++mi) {
      const int m = 64 * wr + 16 * mi + l15;
      af[mi] = *(const s16x8*)(ldsA + m * 32 + ((g ^ SWZ4(m)) << 3));
    }
#pragma unroll
    for (int nj = 0; nj < 4; ++nj) {
      const int n = 64 * wc + 16 * nj + l15;
      bfv[nj] = *(const s16x8*)(Bp + n * 32 + ((g ^ SWZ4(n)) << 3));
    }
#pragma unroll
    for (int mi = 0; mi < 4; ++mi)
#pragma unroll
      for (int nj = 0; nj < 4; ++nj)
        acc[mi][nj] = mfma16(af[mi], bfv[nj], acc[mi][nj]);
  }

  // epilogue: atomic accumulate into this XCD's partial buffer
#pragma unroll
  for (int mi = 0; mi < 4; ++mi)
#pragma unroll
    for (int nj = 0; nj < 4; ++nj) {
      const int n = nb * 128 + 64 * wc + 16 * nj + l15;
#pragma unroll
      for (int r = 0; r < 4; ++r) {
        const int m = mb * 128 + 64 * wr + 16 * mi + 4 * g + r;
        atomicAdd(&C[(size_t)m * D + n], acc[mi][nj][r]);
      }
    }
}

// ---------------------------------------------------------------------------
// Kernel 2: M = max(0.1*run + (0.9/N)*sum_p Cpart[p], 1e-5); sMax = max rowsum
// ---------------------------------------------------------------------------
__global__ __launch_bounds__(256) void prep_k(const float* __restrict__ Cpart,
                                              const float* __restrict__ run,
                                              float* __restrict__ M,
                                              unsigned* __restrict__ sMax) {
  const int r = blockIdx.x;
  const int t = threadIdx.x;
  const float cs = 0.9f / (float)N_ROWS;
  float sum = 0.f;
  for (int c = t; c < D; c += 256) {
    const int rr = r < c ? r : c;
    const int cc = r < c ? c : r;
    float cv = 0.f;
#pragma unroll
    for (int p = 0; p < 8; ++p)
      cv += Cpart[(size_t)p * D * D + (size_t)rr * D + cc];
    float v = 0.1f * run[(size_t)r * D + c] + cs * cv;
    v = fmaxf(v, 1e-5f);
    M[(size_t)r * D + c] = v;
    sum += v;  // all entries positive after clamp
  }
  __shared__ float red[256];
  red[t] = sum;
  __syncthreads();
  for (int off = 128; off > 0; off >>= 1) {
    if (t < off) red[t] += red[t + off];
    __syncthreads();
  }
  if (t == 0) atomicMax(sMax, __float_as_uint(red[0]));
}

// ---------------------------------------------------------------------------
// Kernel 3: iter-1 shortcut. Y0 = M/s; T1 = 1.5I - 0.5*Y0; Z1 = T1.
// ---------------------------------------------------------------------------
__global__ __launch_bounds__(256) void init2_k(const float* __restrict__ M,
                                               const unsigned* __restrict__ sMax,
                                               float* __restrict__ Y0,
                                               float* __restrict__ T,
                                               float* __restrict__ Z1) {
  const float inv = 1.0f / __uint_as_float(*sMax);
  const int i0 = (blockIdx.x * 256 + threadIdx.x) * 4;
  const float4 m4 = *(const float4*)&M[i0];
  const int row = i0 >> 9, col0 = i0 & 511;
  float y[4], tv[4];
#pragma unroll
  for (int e = 0; e < 4; ++e) {
    y[e] = (&m4.x)[e] * inv;
    tv[e] = (row == col0 + e ? 1.5f : 0.f) - 0.5f * y[e];
  }
  *(float4*)&Y0[i0] = make_float4(y[0], y[1], y[2], y[3]);
  const float4 t4 = make_float4(tv[0], tv[1], tv[2], tv[3]);
  *(float4*)&T[i0] = t4;
  *(float4*)&Z1[i0] = t4;
}

// ---------------------------------------------------------------------------
// 512x512x512 fp32 matmul body (32x32 tile / block, 2x2 per thread)
// ---------------------------------------------------------------------------
__device__ __forceinline__ void mm512_body(const float* __restrict__ A,
                                           const float* __restrict__ B,
                                           float* a00, float* a01, float* a10,
                                           float* a11, int rbase, int cbase) {
  __shared__ float As[32][36];
  __shared__ float Bs[32][36];
  const int t = threadIdx.x;
  const int tx = t & 15, ty = t >> 4;
  const int sr = t >> 3, sc = (t & 7) * 4;
  float c00 = 0.f, c01 = 0.f, c10 = 0.f, c11 = 0.f;
  for (int k0 = 0; k0 < D; k0 += 32) {
    __syncthreads();
    *(float4*)&As[sr][sc] = *(const float4*)(A + (size_t)(rbase + sr) * D + k0 + sc);
    *(float4*)&Bs[sr][sc] = *(const float4*)(B + (size_t)(k0 + sr) * D + cbase + sc);
    __syncthreads();
#pragma unroll
    for (int kk = 0; kk < 32; ++kk) {
      const float av0 = As[2 * ty][kk], av1 = As[2 * ty + 1][kk];
      const float2 bv = *(const float2*)&Bs[kk][2 * tx];
      c00 = fmaf(av0, bv.x, c00);
      c01 = fmaf(av0, bv.y, c01);
      c10 = fmaf(av1, bv.x, c10);
      c11 = fmaf(av1, bv.y, c11);
    }
  }
  *a00 = c00; *a01 = c01; *a10 = c10; *a11 = c11;
}

// O = A @ B (plain store)
__global__ __launch_bounds__(256) void mmY_k(const float* __restrict__ A,
                                             const float* __restrict__ B,
                                             float* __restrict__ O) {
  const int rbase = blockIdx.y * 32, cbase = blockIdx.x * 32;
  float a00, a01, a10, a11;
  mm512_body(A, B, &a00, &a01, &a10, &a11, rbase, cbase);
  const int tx = threadIdx.x & 15, ty = threadIdx.x >> 4;
  const int r0 = rbase + 2 * ty, c0 = cbase + 2 * tx;
  O[(size_t)r0 * D + c0] = a00;
  O[(size_t)r0 * D + c0 + 1] = a01;
  O[(size_t)(r0 + 1) * D + c0] = a10;
  O[(size_t)(r0 + 1) * D + c0 + 1] = a11;
}

// T = 1.5 I - 0.5 * (Z @ Y)
__global__ __launch_bounds__(256) void mmT_k(const float* __restrict__ Zm,
                                             const float* __restrict__ Ym,
                                             float* __restrict__ T) {
  const int rbase = blockIdx.y * 32, cbase = blockIdx.x * 32;
  float a00, a01, a10, a11;
  mm512_body(Zm, Ym, &a00, &a01, &a10, &a11, rbase, cbase);
  const int tx = threadIdx.x & 15, ty = threadIdx.x >> 4;
  const int r0 = rbase + 2 * ty, c0 = cbase + 2 * tx;
  T[(size_t)r0 * D + c0] = (r0 == c0 ? 1.5f : 0.f) - 0.5f * a00;
  T[(size_t)r0 * D + c0 + 1] = (r0 == c0 + 1 ? 1.5f : 0.f) - 0.5f * a01;
  T[(size_t)(r0 + 1) * D + c0] = (r0 + 1 == c0 ? 1.5f : 0.f) - 0.5f * a10;
  T[(size_t)(r0 + 1) * D + c0 + 1] = (r0 + 1 == c0 + 1 ? 1.5f : 0.f) - 0.5f * a11;
}

// z=0: Ynew = Y @ T ; z=1: Znew = T @ Z
__global__ __launch_bounds__(256) void mmpair_k(const float* __restrict__ Y,
                                                const float* __restrict__ Z,
                                                const float* __restrict__ T,
                                                float* __restrict__ Yn,
                                                float* __restrict__ Zn) {
  const float* A = blockIdx.z ? T : Y;
  const float* B = blockIdx.z ? Z : T;
  float* O = blockIdx.z ? Zn : Yn;
  const int rbase = blockIdx.y * 32, cbase = blockIdx.x * 32;
  float a00, a01, a10, a11;
  mm512_body(A, B, &a00, &a01, &a10, &a11, rbase, cbase);
  const int tx = threadIdx.x & 15, ty = threadIdx.x >> 4;
  const int r0 = rbase + 2 * ty, c0 = cbase + 2 * tx;
  O[(size_t)r0 * D + c0] = a00;
  O[(size_t)r0 * D + c0 + 1] = a01;
  O[(size_t)(r0 + 1) * D + c0] = a10;
  O[(size_t)(r0 + 1) * D + c0 + 1] = a11;
}

// ---------------------------------------------------------------------------
// Kernel 4 (final NS iter, fused): Zfinal = T @ Z, written directly as
// pre-swizzled bf16 panels scaled by 1/sqrt(s). Y-update skipped (unneeded).
// panel layout: [nb(4)][ks(8)][nl(128)][ch'(8)][e(8)] bf16  (512 KB)
// ---------------------------------------------------------------------------
__global__ __launch_bounds__(256) void mmZp_k(const float* __restrict__ T,
                                              const float* __restrict__ Z,
                                              const unsigned* __restrict__ sMax,
                                              short* __restrict__ panels) {
  const int rbase = blockIdx.y * 32, cbase = blockIdx.x * 32;
  float a00, a01, a10, a11;
  mm512_body(T, Z, &a00, &a01, &a10, &a11, rbase, cbase);
  const float rs = rsqrtf(__uint_as_float(*sMax));
  const int tx = threadIdx.x & 15, ty = threadIdx.x >> 4;
  const int r0 = rbase + 2 * ty, c0 = cbase + 2 * tx;
  const float vv[2][2] = {{a00, a01}, {a10, a11}};
#pragma unroll
  for (int dr = 0; dr < 2; ++dr)
#pragma unroll
    for (int dc = 0; dc < 2; ++dc) {
      const int k = r0 + dr, n = c0 + dc;
      const int nb_ = n >> 7, nl = n & 127;
      const int ks = k >> 6, kl = k & 63;
      const int ch = (kl >> 3) ^ SWZ8(nl), e = kl & 7;
      const size_t pi = (size_t)((nb_ * 8 + ks) * 128 + nl) * 64 + ch * 8 + e;
      panels[pi] = (short)f2bf(vv[dr][dc] * rs);
    }
}

// ---------------------------------------------------------------------------
// Kernel 5: out = x @ B. grid 8192 (XCD swizzle: 4 ct-sharers of a row panel
// co-dispatched on one XCD). USEBF=1: A and B staged via global_load_lds x16
// (A source pre-swizzle-XOR'd per lane, LDS linear). Epilogue: per-wave LDS
// transpose -> lane-contiguous float4 nontemporal stores.
// ---------------------------------------------------------------------------
template <int USEBF>
__global__ __launch_bounds__(256) void gemm_k(const float* __restrict__ x,
                                              const short* __restrict__ xb16,
                                              const short* __restrict__ panels,
                                              float* __restrict__ out) {
  __shared__ short lds[2 * 128 * 64];
  short* ldsA = lds;
  short* ldsB = lds + 128 * 64;

  const int hw = blockIdx.x;
  const int q = hw & 7, j = hw >> 3;
  const int ct = j & 3;
  const int rp = ((j >> 2) << 3) | q;
  const size_t rbase = (size_t)rp * 128;

  const int tid = threadIdx.x;
  const int lane = tid & 63, wave = tid >> 6;
  const int wr = wave >> 1, wc = wave & 1;
  const int l15 = lane & 15, g = lane >> 4;

  // USEBF=0 staging indices
  const int mb8 = tid >> 4;         // 0..15
  const int koff = (tid & 15) * 4;  // 0..60
  const int chA = koff >> 3, subA = koff & 7;

  f32x4 acc[4][4];
#pragma unroll
  for (int i = 0; i < 4; ++i)
#pragma unroll
    for (int j2 = 0; j2 < 4; ++j2) acc[i][j2] = f32x4{0.f, 0.f, 0.f, 0.f};

  const int wrow0 = 32 * wave;

  for (int ks = 0; ks < 8; ++ks) {
    __syncthreads();
    if (USEBF) {
      // A: wave stages rows wrow0..wrow0+31; 4 issues x 1KB; source address
      // carries the XOR swizzle, LDS dest linear.
#pragma unroll
      for (int i = 0; i < 4; ++i) {
        const int m = wrow0 + 8 * i + (lane >> 3);
        const short* src = xb16 + (rbase + m) * D + ks * 64 +
                           (((lane & 7) ^ SWZ8(m)) << 3);
        gld_lds16(src, ldsA + (wrow0 + 8 * i) * 64);
      }
    } else {
      // A from fp32 with inline f2bf
#pragma unroll
      for (int i = 0; i < 8; ++i) {
        const int m = mb8 + (i << 4);
        const float4 v = *(const float4*)(x + (rbase + m) * D + ks * 64 + koff);
        s16x4 p;
        p[0] = (short)f2bf(v.x);
        p[1] = (short)f2bf(v.y);
        p[2] = (short)f2bf(v.z);
        p[3] = (short)f2bf(v.w);
        *(s16x4*)(ldsA + m * 64 + ((chA ^ SWZ8(m)) << 3) + subA) = p;
      }
    }
    // B: linear DMA copy of pre-swizzled panel slice (16 KB)
    {
      const short* src = panels + ((size_t)(ct * 8 + ks) << 13);
#pragma unroll
      for (int i = 0; i < 4; ++i)
        gld_lds16(src + wave * 2048 + i * 512 + lane * 8,
                  ldsB + wave * 2048 + i * 512);
    }
    __syncthreads();

#pragma unroll
    for (int kk = 0; kk < 2; ++kk) {
      s16x8 af[4], bfv[4];
#pragma unroll
      for (int mi = 0; mi < 4; ++mi) {
        const int m = 64 * wr + 16 * mi + l15;
        af[mi] = *(const s16x8*)(ldsA + m * 64 + ((((kk << 2) | g) ^ SWZ8(m)) << 3));
      }
#pragma unroll
      for (int nj = 0; nj < 4; ++nj) {
        const int n = 64 * wc + 16 * nj + l15;
        bfv[nj] = *(const s16x8*)(ldsB + n * 64 + ((((kk << 2) | g) ^ SWZ8(n)) << 3));
      }
#pragma unroll
      for (int mi = 0; mi < 4; ++mi)
#pragma unroll
        for (int nj = 0; nj < 4; ++nj)
          acc[mi][nj] = mfma16(af[mi], bfv[nj], acc[mi][nj]);
    }
  }

  __syncthreads();  // protect LDS before epilogue reuse

  // epilogue: per-wave transpose through LDS, then contiguous float4 NT stores
  float* scratch = (float*)lds;
  const int wbase = wave * 1088;  // 16 rows x 68 floats per wave
#pragma unroll
  for (int mi = 0; mi < 4; ++mi) {
#pragma unroll
    for (int nj = 0; nj < 4; ++nj)
#pragma unroll
      for (int r = 0; r < 4; ++r)
        scratch[wbase + (4 * g + r) * 68 + 16 * nj + l15] = acc[mi][nj][r];
    __syncthreads();
#pragma unroll
    for (int i = 0; i < 4; ++i) {
      const int rl = g + 4 * i;  // 0..15
      const f32x4 v = *(const f32x4*)&scratch[wbase + rl * 68 + l15 * 4];
      const size_t row_g = rbase + 64 * wr + 16 * mi + rl;
      const int col_g = ct * 128 + 64 * wc + l15 * 4;
      __builtin_nontemporal_store(v, (f32x4*)(out + row_g * D + col_g));
    }
    __syncthreads();
  }
}

// ---------------------------------------------------------------------------
extern "C" void kernel_launch(void* const* d_in, const int* in_sizes, int n_in,
                              void* d_out, int out_size, void* d_ws,
                              size_t ws_size, hipStream_t stream) {
  (void)in_sizes; (void)n_in; (void)out_size;
  const float* x = (const float*)d_in[0];
  const float* run = (const float*)d_in[1];
  float* out = (float*)d_out;
  uint8_t* ws = (uint8_t*)d_ws;

  float* Cpart = (float*)ws;                          // 8 MB (8 x 1MB)
  unsigned* sMax = (unsigned*)(ws + (8u << 20));      // 256 B slot
  float* M = (float*)(ws + (8u << 20) + 256);         // 1 MB
  float* Ya = M + 262144;
  float* Yb = Ya + 262144;
  float* Za = Yb + 262144;
  float* Zb = Za + 262144;
  float* T = Zb + 262144;
  short* panels = (short*)(T + 262144);               // 512 KB
  short* xb16 = panels + 262144;                      // 256 MB (optional)

  const size_t need =
      (size_t)((uint8_t*)xb16 - ws) + (size_t)N_ROWS * D * sizeof(short);
  const bool big = ws_size >= need;

  (void)hipMemsetAsync(Cpart, 0, (8u << 20) + 256, stream);

  covar_k<<<1280, 256, 0, stream>>>(x, Cpart, big ? xb16 : nullptr);
  prep_k<<<512, 256, 0, stream>>>(Cpart, run, M, sMax);

  // NS iter 1 (Z0 = I): T1 elementwise, Z1 = T1, Y1 = Y0 @ T1
  init2_k<<<256, 256, 0, stream>>>(M, sMax, Ya, T, Za);
  mmY_k<<<dim3(16, 16), 256, 0, stream>>>(Ya, T, Yb);

  // NS iters 2..NS_ITERS-1 (full coupled)
  float *Y = Yb, *Z = Za, *Yn = Ya, *Zn = Zb;
  for (int it = 1; it < NS_ITERS - 1; ++it) {
    mmT_k<<<dim3(16, 16), 256, 0, stream>>>(Z, Y, T);
    mmpair_k<<<dim3(16, 16, 2), 256, 0, stream>>>(Y, Z, T, Yn, Zn);
    float* t1 = Y; Y = Yn; Yn = t1;
    t1 = Z; Z = Zn; Zn = t1;
  }

  // final NS iter: only Z needed; fused panel build
  mmT_k<<<dim3(16, 16), 256, 0, stream>>>(Z, Y, T);
  mmZp_k<<<dim3(16, 16), 256, 0, stream>>>(T, Z, sMax, panels);

  if (big)
    gemm_k<1><<<8192, 256, 0, stream>>>(x, xb16, panels, out);
  else
    gemm_k<0><<<8192, 256, 0, stream>>>(x, xb16, panels, out);
}

// Round 9
// 675.406 us; speedup vs baseline: 1.2528x; 1.2528x over previous
//
#include <hip/hip_runtime.h>
#include <stdint.h>

// ---------------------------------------------------------------------------
// BatchWhiten: out = x @ inv_sqrtm(max(0.1*running + 0.9*(x^T x)/N, 1e-5))
// x: [262144, 512] fp32, running: [512,512] fp32, out: [262144,512] fp32
// ---------------------------------------------------------------------------

#define N_ROWS 262144
#define D 512
#define NS_ITERS 3  // 1 simplified (Z0=I) + 1 full + 1 final Z-only (fused)
#define CK_CHUNKS 128
#define CK_ROWS (N_ROWS / CK_CHUNKS)  // 2048
#define BKC 32
#define CK_STEPS (CK_ROWS / BKC)      // 64

typedef float f32x4 __attribute__((ext_vector_type(4)));
typedef short s16x8 __attribute__((ext_vector_type(8)));
typedef short s16x4 __attribute__((ext_vector_type(4)));
typedef __bf16 bf16x8 __attribute__((ext_vector_type(8)));

static __device__ __forceinline__ unsigned short f2bf(float f) {
  unsigned u = __float_as_uint(f);
  u += 0x7FFFu + ((u >> 16) & 1u);  // RNE
  return (unsigned short)(u >> 16);
}

static __device__ __forceinline__ f32x4 mfma16(s16x8 a, s16x8 b, f32x4 c) {
  return __builtin_amdgcn_mfma_f32_16x16x32_bf16(
      __builtin_bit_cast(bf16x8, a), __builtin_bit_cast(bf16x8, b), c, 0, 0, 0);
}

// async global->LDS, 16B per lane; LDS dest = wave-uniform base + lane*16
static __device__ __forceinline__ void gld_lds16(const void* g, void* l) {
  __builtin_amdgcn_global_load_lds(
      (const __attribute__((address_space(1))) void*)g,
      (__attribute__((address_space(3))) void*)l, 16, 0, 0);
}

#define SWZ4(c) (((c) ^ ((c) >> 2)) & 3)
#define SWZ8(c) (((c) ^ ((c) >> 3)) & 7)

// ---------------------------------------------------------------------------
// Kernel 1: Cpart[xcd] += x^T x (split-K, bf16 MFMA, upper tiles mb<=nb).
// grid 1280 (10 tiles x 128 chunks), BK=32. Register prefetch: next step's
// loads are issued RIGHT AFTER the convert consumes the buffer (no WAR), so
// ~900cy HBM latency hides under barrier+ds_write+dump+barrier+MFMA. No
// occupancy cap — r8's __launch_bounds__(256,4) spilled the buffers to
// scratch (WRITE +190MB); VGPR must stay free (~140).
// XCD-swizzled: a chunk's 10 works at hw-stride-8 share one XCD's L2.
// xb16 dump balanced: each tile's 4 stagers (ranks 0..3) dump the kh==rank
// 8-row quarter per step; dump stores nontemporal.
// ---------------------------------------------------------------------------
__global__ __launch_bounds__(256) void covar_k(const float* __restrict__ x,
                                               float* __restrict__ Cpart,
                                               short* __restrict__ xb16) {
  __shared__ short ldsA[128 * 32];
  __shared__ short ldsB[128 * 32];

  // bijective XCD swizzle: 1280 works = 8 XCDs x 160
  const int hw = blockIdx.x;
  const int work = (hw & 7) * 160 + (hw >> 3);
  int t = work % 10, mb = 0, rl = 4;
  while (t >= rl) { t -= rl; ++mb; --rl; }
  const int nb = mb + t;
  const int chunk = work / 10;
  float* C = Cpart + (size_t)(hw & 7) * (D * D);

  const int tid = threadIdx.x;
  const int c2 = (tid & 63) * 2;  // columns c2, c2+1 of the tile
  const int kh = tid >> 6;        // 0..3: rows [8kh, 8kh+8) of the step

  const int lane = tid & 63;
  const int wave = tid >> 6;
  const int wr = wave >> 1, wc = wave & 1;
  const int l15 = lane & 15, g = lane >> 4;

  const bool offd = (nb != mb);
  const bool haveDump = (xb16 != nullptr);
  const int rankA = nb - mb;        // 0 for diagonal works
  const int rankB = 4 - (nb - mb);  // only meaningful off-diagonal
  const bool dumpA = haveDump && (kh == rankA);
  const bool dumpB = haveDump && offd && (kh == rankB);
  uint32_t* xw = (uint32_t*)xb16;

  f32x4 acc[4][4];
#pragma unroll
  for (int i = 0; i < 4; ++i)
#pragma unroll
    for (int j = 0; j < 4; ++j) acc[i][j] = f32x4{0.f, 0.f, 0.f, 0.f};

  const size_t kbase0 = (size_t)chunk * CK_ROWS;

  // register prefetch buffers
  float2 bufM[8], bufN[8];
  {
    const float* srcM = x + (kbase0 + kh * 8) * D + mb * 128 + c2;
#pragma unroll
    for (int q = 0; q < 8; ++q) bufM[q] = *(const float2*)(srcM + (size_t)q * D);
    if (offd) {
      const float* srcN = x + (kbase0 + kh * 8) * D + nb * 128 + c2;
#pragma unroll
      for (int q = 0; q < 8; ++q) bufN[q] = *(const float2*)(srcN + (size_t)q * D);
    }
  }

  for (int st = 0; st < CK_STEPS; ++st) {
    const size_t k0 = kbase0 + (size_t)st * BKC;

    // convert current step's registers to bf16 (loads already landed)
    s16x8 pM0, pM1, pN0, pN1;
#pragma unroll
    for (int q = 0; q < 8; ++q) {
      pM0[q] = (short)f2bf(bufM[q].x);
      pM1[q] = (short)f2bf(bufM[q].y);
    }
    if (offd) {
#pragma unroll
      for (int q = 0; q < 8; ++q) {
        pN0[q] = (short)f2bf(bufN[q].x);
        pN1[q] = (short)f2bf(bufN[q].y);
      }
    }

    // issue NEXT step's loads NOW (bufM/bufN are dead after the convert) —
    // latency hides under barrier + ds_write + dump + barrier + MFMA
    if (st + 1 < CK_STEPS) {
      const float* srcM = x + (k0 + BKC + kh * 8) * D + mb * 128 + c2;
#pragma unroll
      for (int q = 0; q < 8; ++q)
        bufM[q] = *(const float2*)(srcM + (size_t)q * D);
      if (offd) {
        const float* srcN = x + (k0 + BKC + kh * 8) * D + nb * 128 + c2;
#pragma unroll
        for (int q = 0; q < 8; ++q)
          bufN[q] = *(const float2*)(srcN + (size_t)q * D);
      }
    }

    __syncthreads();  // MFMA of st-1 finished reading LDS
    *(s16x8*)(ldsA + c2 * 32 + ((kh ^ SWZ4(c2)) << 3)) = pM0;
    *(s16x8*)(ldsA + (c2 + 1) * 32 + ((kh ^ SWZ4(c2 + 1)) << 3)) = pM1;
    if (offd) {
      *(s16x8*)(ldsB + c2 * 32 + ((kh ^ SWZ4(c2)) << 3)) = pN0;
      *(s16x8*)(ldsB + (c2 + 1) * 32 + ((kh ^ SWZ4(c2 + 1)) << 3)) = pN1;
    }
    if (dumpA) {
#pragma unroll
      for (int q = 0; q < 8; ++q) {
        const uint32_t u =
            (uint32_t)(uint16_t)pM0[q] | ((uint32_t)(uint16_t)pM1[q] << 16);
        __builtin_nontemporal_store(
            u, &xw[(k0 + kh * 8 + q) * 256 + mb * 64 + (c2 >> 1)]);
      }
    }
    if (dumpB) {
#pragma unroll
      for (int q = 0; q < 8; ++q) {
        const uint32_t u =
            (uint32_t)(uint16_t)pN0[q] | ((uint32_t)(uint16_t)pN1[q] << 16);
        __builtin_nontemporal_store(
            u, &xw[(k0 + kh * 8 + q) * 256 + nb * 64 + (c2 >> 1)]);
      }
    }
    __syncthreads();

    // MFMA on current LDS tiles
    const short* Bp = offd ? ldsB : ldsA;
    s16x8 af[4], bfv[4];
#pragma unroll
    for (int mi = 0; mi < 4; ++mi) {
      const int m = 64 * wr + 16 * mi + l15;
      af[mi] = *(const s16x8*)(ldsA + m * 32 + ((g ^ SWZ4(m)) << 3));
    }
#pragma unroll
    for (int nj = 0; nj < 4; ++nj) {
      const int n = 64 * wc + 16 * nj + l15;
      bfv[nj] = *(const s16x8*)(Bp + n * 32 + ((g ^ SWZ4(n)) << 3));
    }
#pragma unroll
    for (int mi = 0; mi < 4; ++mi)
#pragma unroll
      for (int nj = 0; nj < 4; ++nj)
        acc[mi][nj] = mfma16(af[mi], bfv[nj], acc[mi][nj]);
  }

  // epilogue: atomic accumulate into this XCD's partial buffer
#pragma unroll
  for (int mi = 0; mi < 4; ++mi)
#pragma unroll
    for (int nj = 0; nj < 4; ++nj) {
      const int n = nb * 128 + 64 * wc + 16 * nj + l15;
#pragma unroll
      for (int r = 0; r < 4; ++r) {
        const int m = mb * 128 + 64 * wr + 16 * mi + 4 * g + r;
        atomicAdd(&C[(size_t)m * D + n], acc[mi][nj][r]);
      }
    }
}

// ---------------------------------------------------------------------------
// Kernel 2: M = max(0.1*run + (0.9/N)*sum_p Cpart[p], 1e-5); sMax = max rowsum
// ---------------------------------------------------------------------------
__global__ __launch_bounds__(256) void prep_k(const float* __restrict__ Cpart,
                                              const float* __restrict__ run,
                                              float* __restrict__ M,
                                              unsigned* __restrict__ sMax) {
  const int r = blockIdx.x;
  const int t = threadIdx.x;
  const float cs = 0.9f / (float)N_ROWS;
  float sum = 0.f;
  for (int c = t; c < D; c += 256) {
    const int rr = r < c ? r : c;
    const int cc = r < c ? c : r;
    float cv = 0.f;
#pragma unroll
    for (int p = 0; p < 8; ++p)
      cv += Cpart[(size_t)p * D * D + (size_t)rr * D + cc];
    float v = 0.1f * run[(size_t)r * D + c] + cs * cv;
    v = fmaxf(v, 1e-5f);
    M[(size_t)r * D + c] = v;
    sum += v;  // all entries positive after clamp
  }
  __shared__ float red[256];
  red[t] = sum;
  __syncthreads();
  for (int off = 128; off > 0; off >>= 1) {
    if (t < off) red[t] += red[t + off];
    __syncthreads();
  }
  if (t == 0) atomicMax(sMax, __float_as_uint(red[0]));
}

// ---------------------------------------------------------------------------
// Kernel 3: iter-1 shortcut. Y0 = M/s; T1 = 1.5I - 0.5*Y0; Z1 = T1.
// ---------------------------------------------------------------------------
__global__ __launch_bounds__(256) void init2_k(const float* __restrict__ M,
                                               const unsigned* __restrict__ sMax,
                                               float* __restrict__ Y0,
                                               float* __restrict__ T,
                                               float* __restrict__ Z1) {
  const float inv = 1.0f / __uint_as_float(*sMax);
  const int i0 = (blockIdx.x * 256 + threadIdx.x) * 4;
  const float4 m4 = *(const float4*)&M[i0];
  const int row = i0 >> 9, col0 = i0 & 511;
  float y[4], tv[4];
#pragma unroll
  for (int e = 0; e < 4; ++e) {
    y[e] = (&m4.x)[e] * inv;
    tv[e] = (row == col0 + e ? 1.5f : 0.f) - 0.5f * y[e];
  }
  *(float4*)&Y0[i0] = make_float4(y[0], y[1], y[2], y[3]);
  const float4 t4 = make_float4(tv[0], tv[1], tv[2], tv[3]);
  *(float4*)&T[i0] = t4;
  *(float4*)&Z1[i0] = t4;
}

// ---------------------------------------------------------------------------
// 512x512x512 fp32 matmul body (32x32 tile / block, 2x2 per thread)
// ---------------------------------------------------------------------------
__device__ __forceinline__ void mm512_body(const float* __restrict__ A,
                                           const float* __restrict__ B,
                                           float* a00, float* a01, float* a10,
                                           float* a11, int rbase, int cbase) {
  __shared__ float As[32][36];
  __shared__ float Bs[32][36];
  const int t = threadIdx.x;
  const int tx = t & 15, ty = t >> 4;
  const int sr = t >> 3, sc = (t & 7) * 4;
  float c00 = 0.f, c01 = 0.f, c10 = 0.f, c11 = 0.f;
  for (int k0 = 0; k0 < D; k0 += 32) {
    __syncthreads();
    *(float4*)&As[sr][sc] = *(const float4*)(A + (size_t)(rbase + sr) * D + k0 + sc);
    *(float4*)&Bs[sr][sc] = *(const float4*)(B + (size_t)(k0 + sr) * D + cbase + sc);
    __syncthreads();
#pragma unroll
    for (int kk = 0; kk < 32; ++kk) {
      const float av0 = As[2 * ty][kk], av1 = As[2 * ty + 1][kk];
      const float2 bv = *(const float2*)&Bs[kk][2 * tx];
      c00 = fmaf(av0, bv.x, c00);
      c01 = fmaf(av0, bv.y, c01);
      c10 = fmaf(av1, bv.x, c10);
      c11 = fmaf(av1, bv.y, c11);
    }
  }
  *a00 = c00; *a01 = c01; *a10 = c10; *a11 = c11;
}

// O = A @ B (plain store)
__global__ __launch_bounds__(256) void mmY_k(const float* __restrict__ A,
                                             const float* __restrict__ B,
                                             float* __restrict__ O) {
  const int rbase = blockIdx.y * 32, cbase = blockIdx.x * 32;
  float a00, a01, a10, a11;
  mm512_body(A, B, &a00, &a01, &a10, &a11, rbase, cbase);
  const int tx = threadIdx.x & 15, ty = threadIdx.x >> 4;
  const int r0 = rbase + 2 * ty, c0 = cbase + 2 * tx;
  O[(size_t)r0 * D + c0] = a00;
  O[(size_t)r0 * D + c0 + 1] = a01;
  O[(size_t)(r0 + 1) * D + c0] = a10;
  O[(size_t)(r0 + 1) * D + c0 + 1] = a11;
}

// T = 1.5 I - 0.5 * (Z @ Y)
__global__ __launch_bounds__(256) void mmT_k(const float* __restrict__ Zm,
                                             const float* __restrict__ Ym,
                                             float* __restrict__ T) {
  const int rbase = blockIdx.y * 32, cbase = blockIdx.x * 32;
  float a00, a01, a10, a11;
  mm512_body(Zm, Ym, &a00, &a01, &a10, &a11, rbase, cbase);
  const int tx = threadIdx.x & 15, ty = threadIdx.x >> 4;
  const int r0 = rbase + 2 * ty, c0 = cbase + 2 * tx;
  T[(size_t)r0 * D + c0] = (r0 == c0 ? 1.5f : 0.f) - 0.5f * a00;
  T[(size_t)r0 * D + c0 + 1] = (r0 == c0 + 1 ? 1.5f : 0.f) - 0.5f * a01;
  T[(size_t)(r0 + 1) * D + c0] = (r0 + 1 == c0 ? 1.5f : 0.f) - 0.5f * a10;
  T[(size_t)(r0 + 1) * D + c0 + 1] = (r0 + 1 == c0 + 1 ? 1.5f : 0.f) - 0.5f * a11;
}

// z=0: Ynew = Y @ T ; z=1: Znew = T @ Z
__global__ __launch_bounds__(256) void mmpair_k(const float* __restrict__ Y,
                                                const float* __restrict__ Z,
                                                const float* __restrict__ T,
                                                float* __restrict__ Yn,
                                                float* __restrict__ Zn) {
  const float* A = blockIdx.z ? T : Y;
  const float* B = blockIdx.z ? Z : T;
  float* O = blockIdx.z ? Zn : Yn;
  const int rbase = blockIdx.y * 32, cbase = blockIdx.x * 32;
  float a00, a01, a10, a11;
  mm512_body(A, B, &a00, &a01, &a10, &a11, rbase, cbase);
  const int tx = threadIdx.x & 15, ty = threadIdx.x >> 4;
  const int r0 = rbase + 2 * ty, c0 = cbase + 2 * tx;
  O[(size_t)r0 * D + c0] = a00;
  O[(size_t)r0 * D + c0 + 1] = a01;
  O[(size_t)(r0 + 1) * D + c0] = a10;
  O[(size_t)(r0 + 1) * D + c0 + 1] = a11;
}

// ---------------------------------------------------------------------------
// Kernel 4 (final NS iter, fused): Zfinal = T @ Z, written directly as
// pre-swizzled bf16 panels scaled by 1/sqrt(s). Y-update skipped (unneeded).
// panel layout: [nb(4)][ks(8)][nl(128)][ch'(8)][e(8)] bf16  (512 KB)
// ---------------------------------------------------------------------------
__global__ __launch_bounds__(256) void mmZp_k(const float* __restrict__ T,
                                              const float* __restrict__ Z,
                                              const unsigned* __restrict__ sMax,
                                              short* __restrict__ panels) {
  const int rbase = blockIdx.y * 32, cbase = blockIdx.x * 32;
  float a00, a01, a10, a11;
  mm512_body(T, Z, &a00, &a01, &a10, &a11, rbase, cbase);
  const float rs = rsqrtf(__uint_as_float(*sMax));
  const int tx = threadIdx.x & 15, ty = threadIdx.x >> 4;
  const int r0 = rbase + 2 * ty, c0 = cbase + 2 * tx;
  const float vv[2][2] = {{a00, a01}, {a10, a11}};
#pragma unroll
  for (int dr = 0; dr < 2; ++dr)
#pragma unroll
    for (int dc = 0; dc < 2; ++dc) {
      const int k = r0 + dr, n = c0 + dc;
      const int nb_ = n >> 7, nl = n & 127;
      const int ks = k >> 6, kl = k & 63;
      const int ch = (kl >> 3) ^ SWZ8(nl), e = kl & 7;
      const size_t pi = (size_t)((nb_ * 8 + ks) * 128 + nl) * 64 + ch * 8 + e;
      panels[pi] = (short)f2bf(vv[dr][dc] * rs);
    }
}

// ---------------------------------------------------------------------------
// Kernel 5: out = x @ B. grid 8192 (XCD swizzle: 4 ct-sharers of a row panel
// co-dispatched on one XCD). USEBF=1: A and B staged via global_load_lds x16
// (A source pre-swizzle-XOR'd per lane, LDS linear). Epilogue: per-wave LDS
// transpose -> lane-contiguous float4 nontemporal stores.
// ---------------------------------------------------------------------------
template <int USEBF>
__global__ __launch_bounds__(256) void gemm_k(const float* __restrict__ x,
                                              const short* __restrict__ xb16,
                                              const short* __restrict__ panels,
                                              float* __restrict__ out) {
  __shared__ short lds[2 * 128 * 64];
  short* ldsA = lds;
  short* ldsB = lds + 128 * 64;

  const int hw = blockIdx.x;
  const int q = hw & 7, j = hw >> 3;
  const int ct = j & 3;
  const int rp = ((j >> 2) << 3) | q;
  const size_t rbase = (size_t)rp * 128;

  const int tid = threadIdx.x;
  const int lane = tid & 63, wave = tid >> 6;
  const int wr = wave >> 1, wc = wave & 1;
  const int l15 = lane & 15, g = lane >> 4;

  // USEBF=0 staging indices
  const int mb8 = tid >> 4;         // 0..15
  const int koff = (tid & 15) * 4;  // 0..60
  const int chA = koff >> 3, subA = koff & 7;

  f32x4 acc[4][4];
#pragma unroll
  for (int i = 0; i < 4; ++i)
#pragma unroll
    for (int j2 = 0; j2 < 4; ++j2) acc[i][j2] = f32x4{0.f, 0.f, 0.f, 0.f};

  const int wrow0 = 32 * wave;

  for (int ks = 0; ks < 8; ++ks) {
    __syncthreads();
    if (USEBF) {
      // A: wave stages rows wrow0..wrow0+31; 4 issues x 1KB; source address
      // carries the XOR swizzle, LDS dest linear.
#pragma unroll
      for (int i = 0; i < 4; ++i) {
        const int m = wrow0 + 8 * i + (lane >> 3);
        const short* src = xb16 + (rbase + m) * D + ks * 64 +
                           (((lane & 7) ^ SWZ8(m)) << 3);
        gld_lds16(src, ldsA + (wrow0 + 8 * i) * 64);
      }
    } else {
      // A from fp32 with inline f2bf
#pragma unroll
      for (int i = 0; i < 8; ++i) {
        const int m = mb8 + (i << 4);
        const float4 v = *(const float4*)(x + (rbase + m) * D + ks * 64 + koff);
        s16x4 p;
        p[0] = (short)f2bf(v.x);
        p[1] = (short)f2bf(v.y);
        p[2] = (short)f2bf(v.z);
        p[3] = (short)f2bf(v.w);
        *(s16x4*)(ldsA + m * 64 + ((chA ^ SWZ8(m)) << 3) + subA) = p;
      }
    }
    // B: linear DMA copy of pre-swizzled panel slice (16 KB)
    {
      const short* src = panels + ((size_t)(ct * 8 + ks) << 13);
#pragma unroll
      for (int i = 0; i < 4; ++i)
        gld_lds16(src + wave * 2048 + i * 512 + lane * 8,
                  ldsB + wave * 2048 + i * 512);
    }
    __syncthreads();

#pragma unroll
    for (int kk = 0; kk < 2; ++kk) {
      s16x8 af[4], bfv[4];
#pragma unroll
      for (int mi = 0; mi < 4; ++mi) {
        const int m = 64 * wr + 16 * mi + l15;
        af[mi] = *(const s16x8*)(ldsA + m * 64 + ((((kk << 2) | g) ^ SWZ8(m)) << 3));
      }
#pragma unroll
      for (int nj = 0; nj < 4; ++nj) {
        const int n = 64 * wc + 16 * nj + l15;
        bfv[nj] = *(const s16x8*)(ldsB + n * 64 + ((((kk << 2) | g) ^ SWZ8(n)) << 3));
      }
#pragma unroll
      for (int mi = 0; mi < 4; ++mi)
#pragma unroll
        for (int nj = 0; nj < 4; ++nj)
          acc[mi][nj] = mfma16(af[mi], bfv[nj], acc[mi][nj]);
    }
  }

  __syncthreads();  // protect LDS before epilogue reuse

  // epilogue: per-wave transpose through LDS, then contiguous float4 NT stores
  float* scratch = (float*)lds;
  const int wbase = wave * 1088;  // 16 rows x 68 floats per wave
#pragma unroll
  for (int mi = 0; mi < 4; ++mi) {
#pragma unroll
    for (int nj = 0; nj < 4; ++nj)
#pragma unroll
      for (int r = 0; r < 4; ++r)
        scratch[wbase + (4 * g + r) * 68 + 16 * nj + l15] = acc[mi][nj][r];
    __syncthreads();
#pragma unroll
    for (int i = 0; i < 4; ++i) {
      const int rl = g + 4 * i;  // 0..15
      const f32x4 v = *(const f32x4*)&scratch[wbase + rl * 68 + l15 * 4];
      const size_t row_g = rbase + 64 * wr + 16 * mi + rl;
      const int col_g = ct * 128 + 64 * wc + l15 * 4;
      __builtin_nontemporal_store(v, (f32x4*)(out + row_g * D + col_g));
    }
    __syncthreads();
  }
}

// ---------------------------------------------------------------------------
extern "C" void kernel_launch(void* const* d_in, const int* in_sizes, int n_in,
                              void* d_out, int out_size, void* d_ws,
                              size_t ws_size, hipStream_t stream) {
  (void)in_sizes; (void)n_in; (void)out_size;
  const float* x = (const float*)d_in[0];
  const float* run = (const float*)d_in[1];
  float* out = (float*)d_out;
  uint8_t* ws = (uint8_t*)d_ws;

  float* Cpart = (float*)ws;                          // 8 MB (8 x 1MB)
  unsigned* sMax = (unsigned*)(ws + (8u << 20));      // 256 B slot
  float* M = (float*)(ws + (8u << 20) + 256);         // 1 MB
  float* Ya = M + 262144;
  float* Yb = Ya + 262144;
  float* Za = Yb + 262144;
  float* Zb = Za + 262144;
  float* T = Zb + 262144;
  short* panels = (short*)(T + 262144);               // 512 KB
  short* xb16 = panels + 262144;                      // 256 MB (optional)

  const size_t need =
      (size_t)((uint8_t*)xb16 - ws) + (size_t)N_ROWS * D * sizeof(short);
  const bool big = ws_size >= need;

  (void)hipMemsetAsync(Cpart, 0, (8u << 20) + 256, stream);

  covar_k<<<1280, 256, 0, stream>>>(x, Cpart, big ? xb16 : nullptr);
  prep_k<<<512, 256, 0, stream>>>(Cpart, run, M, sMax);

  // NS iter 1 (Z0 = I): T1 elementwise, Z1 = T1, Y1 = Y0 @ T1
  init2_k<<<256, 256, 0, stream>>>(M, sMax, Ya, T, Za);
  mmY_k<<<dim3(16, 16), 256, 0, stream>>>(Ya, T, Yb);

  // NS iters 2..NS_ITERS-1 (full coupled)
  float *Y = Yb, *Z = Za, *Yn = Ya, *Zn = Zb;
  for (int it = 1; it < NS_ITERS - 1; ++it) {
    mmT_k<<<dim3(16, 16), 256, 0, stream>>>(Z, Y, T);
    mmpair_k<<<dim3(16, 16, 2), 256, 0, stream>>>(Y, Z, T, Yn, Zn);
    float* t1 = Y; Y = Yn; Yn = t1;
    t1 = Z; Z = Zn; Zn = t1;
  }

  // final NS iter: only Z needed; fused panel build
  mmT_k<<<dim3(16, 16), 256, 0, stream>>>(Z, Y, T);
  mmZp_k<<<dim3(16, 16), 256, 0, stream>>>(T, Z, sMax, panels);

  if (big)
    gemm_k<1><<<8192, 256, 0, stream>>>(x, xb16, panels, out);
  else
    gemm_k<0><<<8192, 256, 0, stream>>>(x, xb16, panels, out);
}

// Round 10
// 610.609 us; speedup vs baseline: 1.3857x; 1.1061x over previous
//
#include <hip/hip_runtime.h>
#include <stdint.h>

// ---------------------------------------------------------------------------
// BatchWhiten: out = x @ inv_sqrtm(max(0.1*running + 0.9*(x^T x)/N, 1e-5))
// x: [262144, 512] fp32, running: [512,512] fp32, out: [262144,512] fp32
// ---------------------------------------------------------------------------

#define N_ROWS 262144
#define D 512
#define NS_ITERS 3  // 1 simplified (Z0=I) + 1 full + 1 final Z-only (fused)
#define CK_CHUNKS 128
#define CK_ROWS (N_ROWS / CK_CHUNKS)  // 2048
#define BKC 32
#define CK_STEPS (CK_ROWS / BKC)      // 64

typedef float f32x4 __attribute__((ext_vector_type(4)));
typedef short s16x8 __attribute__((ext_vector_type(8)));
typedef short s16x4 __attribute__((ext_vector_type(4)));
typedef __bf16 bf16x8 __attribute__((ext_vector_type(8)));

static __device__ __forceinline__ unsigned short f2bf(float f) {
  unsigned u = __float_as_uint(f);
  u += 0x7FFFu + ((u >> 16) & 1u);  // RNE
  return (unsigned short)(u >> 16);
}

static __device__ __forceinline__ f32x4 mfma16(s16x8 a, s16x8 b, f32x4 c) {
  return __builtin_amdgcn_mfma_f32_16x16x32_bf16(
      __builtin_bit_cast(bf16x8, a), __builtin_bit_cast(bf16x8, b), c, 0, 0, 0);
}

// async global->LDS, 16B per lane; LDS dest = wave-uniform base + lane*16
static __device__ __forceinline__ void gld_lds16(const void* g, void* l) {
  __builtin_amdgcn_global_load_lds(
      (const __attribute__((address_space(1))) void*)g,
      (__attribute__((address_space(3))) void*)l, 16, 0, 0);
}

#define SWZ4(c) (((c) ^ ((c) >> 2)) & 3)
#define SWZ8(c) (((c) ^ ((c) >> 3)) & 7)

// raw barrier, LDS-writes published, NO vmcnt drain (prefetch spans barrier)
static __device__ __forceinline__ void bar_lgkm() {
  asm volatile("s_waitcnt lgkmcnt(0)" ::: "memory");
  __builtin_amdgcn_s_barrier();
  __builtin_amdgcn_sched_barrier(0);
}

// ---------------------------------------------------------------------------
// Kernel 1: Cpart[xcd] += x^T x (split-K, bf16 MFMA, upper tiles mb<=nb).
// grid 1280 (10 tiles x 128 chunks), BK=32. LDS DOUBLE-BUFFER + ONE raw
// barrier per step (lgkmcnt only — __syncthreads' vmcnt(0) drain was killing
// the register prefetch, r7==r9==331us). Next step's reg loads issued after
// the convert; their ~900cy latency now truly spans the barrier + MFMA.
// XCD-swizzled: a chunk's 10 works at hw-stride-8 share one XCD's L2.
// xb16 dump balanced: each tile's 4 stagers (ranks 0..3) dump the kh==rank
// 8-row quarter per step; dump stores nontemporal.
// ---------------------------------------------------------------------------
__global__ __launch_bounds__(256) void covar_k(const float* __restrict__ x,
                                               float* __restrict__ Cpart,
                                               short* __restrict__ xb16) {
  __shared__ short ldsA[2][128 * 32];
  __shared__ short ldsB[2][128 * 32];

  // bijective XCD swizzle: 1280 works = 8 XCDs x 160
  const int hw = blockIdx.x;
  const int work = (hw & 7) * 160 + (hw >> 3);
  int t = work % 10, mb = 0, rl = 4;
  while (t >= rl) { t -= rl; ++mb; --rl; }
  const int nb = mb + t;
  const int chunk = work / 10;
  float* C = Cpart + (size_t)(hw & 7) * (D * D);

  const int tid = threadIdx.x;
  const int c2 = (tid & 63) * 2;  // columns c2, c2+1 of the tile
  const int kh = tid >> 6;        // 0..3: rows [8kh, 8kh+8) of the step

  const int lane = tid & 63;
  const int wave = tid >> 6;
  const int wr = wave >> 1, wc = wave & 1;
  const int l15 = lane & 15, g = lane >> 4;

  const bool offd = (nb != mb);
  const bool haveDump = (xb16 != nullptr);
  const int rankA = nb - mb;
  const int rankB = 4 - (nb - mb);
  const bool dumpA = haveDump && (kh == rankA);
  const bool dumpB = haveDump && offd && (kh == rankB);
  uint32_t* xw = (uint32_t*)xb16;

  f32x4 acc[4][4];
#pragma unroll
  for (int i = 0; i < 4; ++i)
#pragma unroll
    for (int j = 0; j < 4; ++j) acc[i][j] = f32x4{0.f, 0.f, 0.f, 0.f};

  const size_t kbase0 = (size_t)chunk * CK_ROWS;

  // register prefetch buffers
  float2 bufM[8], bufN[8];
  {
    const float* srcM = x + (kbase0 + kh * 8) * D + mb * 128 + c2;
#pragma unroll
    for (int q = 0; q < 8; ++q) bufM[q] = *(const float2*)(srcM + (size_t)q * D);
    if (offd) {
      const float* srcN = x + (kbase0 + kh * 8) * D + nb * 128 + c2;
#pragma unroll
      for (int q = 0; q < 8; ++q) bufN[q] = *(const float2*)(srcN + (size_t)q * D);
    }
  }

  for (int st = 0; st < CK_STEPS; ++st) {
    const size_t k0 = kbase0 + (size_t)st * BKC;

    // convert current step's registers to bf16 (loads already landed)
    s16x8 pM0, pM1, pN0, pN1;
#pragma unroll
    for (int q = 0; q < 8; ++q) {
      pM0[q] = (short)f2bf(bufM[q].x);
      pM1[q] = (short)f2bf(bufM[q].y);
    }
    if (offd) {
#pragma unroll
      for (int q = 0; q < 8; ++q) {
        pN0[q] = (short)f2bf(bufN[q].x);
        pN1[q] = (short)f2bf(bufN[q].y);
      }
    }

    // issue NEXT step's loads (regs dead after convert); with the raw
    // lgkm-only barrier these stay in flight across the whole step
    if (st + 1 < CK_STEPS) {
      const float* srcM = x + (k0 + BKC + kh * 8) * D + mb * 128 + c2;
#pragma unroll
      for (int q = 0; q < 8; ++q)
        bufM[q] = *(const float2*)(srcM + (size_t)q * D);
      if (offd) {
        const float* srcN = x + (k0 + BKC + kh * 8) * D + nb * 128 + c2;
#pragma unroll
        for (int q = 0; q < 8; ++q)
          bufN[q] = *(const float2*)(srcN + (size_t)q * D);
      }
    }

    // double-buffered LDS write (no front barrier needed: every wave's
    // step st-1 ds_reads completed before its own lgkmcnt(0)+barrier(st-1))
    short* wA = ldsA[st & 1];
    short* wB = ldsB[st & 1];
    *(s16x8*)(wA + c2 * 32 + ((kh ^ SWZ4(c2)) << 3)) = pM0;
    *(s16x8*)(wA + (c2 + 1) * 32 + ((kh ^ SWZ4(c2 + 1)) << 3)) = pM1;
    if (offd) {
      *(s16x8*)(wB + c2 * 32 + ((kh ^ SWZ4(c2)) << 3)) = pN0;
      *(s16x8*)(wB + (c2 + 1) * 32 + ((kh ^ SWZ4(c2 + 1)) << 3)) = pN1;
    }
    if (dumpA) {
#pragma unroll
      for (int q = 0; q < 8; ++q) {
        const uint32_t u =
            (uint32_t)(uint16_t)pM0[q] | ((uint32_t)(uint16_t)pM1[q] << 16);
        __builtin_nontemporal_store(
            u, &xw[(k0 + kh * 8 + q) * 256 + mb * 64 + (c2 >> 1)]);
      }
    }
    if (dumpB) {
#pragma unroll
      for (int q = 0; q < 8; ++q) {
        const uint32_t u =
            (uint32_t)(uint16_t)pN0[q] | ((uint32_t)(uint16_t)pN1[q] << 16);
        __builtin_nontemporal_store(
            u, &xw[(k0 + kh * 8 + q) * 256 + nb * 64 + (c2 >> 1)]);
      }
    }

    bar_lgkm();  // publish ds_writes; NO vmcnt drain

    // MFMA on current LDS buffers
    const short* rA = ldsA[st & 1];
    const short* rB = offd ? ldsB[st & 1] : ldsA[st & 1];
    s16x8 af[4], bfv[4];
#pragma unroll
    for (int mi = 0; mi < 4; ++mi) {
      const int m = 64 * wr + 16 * mi + l15;
      af[mi] = *(const s16x8*)(rA + m * 32 + ((g ^ SWZ4(m)) << 3));
    }
#pragma unroll
    for (int nj = 0; nj < 4; ++nj) {
      const int n = 64 * wc + 16 * nj + l15;
      bfv[nj] = *(const s16x8*)(rB + n * 32 + ((g ^ SWZ4(n)) << 3));
    }
#pragma unroll
    for (int mi = 0; mi < 4; ++mi)
#pragma unroll
      for (int nj = 0; nj < 4; ++nj)
        acc[mi][nj] = mfma16(af[mi], bfv[nj], acc[mi][nj]);
  }

  // epilogue: atomic accumulate into this XCD's partial buffer
#pragma unroll
  for (int mi = 0; mi < 4; ++mi)
#pragma unroll
    for (int nj = 0; nj < 4; ++nj) {
      const int n = nb * 128 + 64 * wc + 16 * nj + l15;
#pragma unroll
      for (int r = 0; r < 4; ++r) {
        const int m = mb * 128 + 64 * wr + 16 * mi + 4 * g + r;
        atomicAdd(&C[(size_t)m * D + n], acc[mi][nj][r]);
      }
    }
}

// ---------------------------------------------------------------------------
// Kernel 2: M = max(0.1*run + (0.9/N)*sum_p Cpart[p], 1e-5); sMax = max rowsum
// ---------------------------------------------------------------------------
__global__ __launch_bounds__(256) void prep_k(const float* __restrict__ Cpart,
                                              const float* __restrict__ run,
                                              float* __restrict__ M,
                                              unsigned* __restrict__ sMax) {
  const int r = blockIdx.x;
  const int t = threadIdx.x;
  const float cs = 0.9f / (float)N_ROWS;
  float sum = 0.f;
  for (int c = t; c < D; c += 256) {
    const int rr = r < c ? r : c;
    const int cc = r < c ? c : r;
    float cv = 0.f;
#pragma unroll
    for (int p = 0; p < 8; ++p)
      cv += Cpart[(size_t)p * D * D + (size_t)rr * D + cc];
    float v = 0.1f * run[(size_t)r * D + c] + cs * cv;
    v = fmaxf(v, 1e-5f);
    M[(size_t)r * D + c] = v;
    sum += v;  // all entries positive after clamp
  }
  __shared__ float red[256];
  red[t] = sum;
  __syncthreads();
  for (int off = 128; off > 0; off >>= 1) {
    if (t < off) red[t] += red[t + off];
    __syncthreads();
  }
  if (t == 0) atomicMax(sMax, __float_as_uint(red[0]));
}

// ---------------------------------------------------------------------------
// Kernel 3: iter-1 shortcut. Y0 = M/s; T1 = 1.5I - 0.5*Y0; Z1 = T1.
// ---------------------------------------------------------------------------
__global__ __launch_bounds__(256) void init2_k(const float* __restrict__ M,
                                               const unsigned* __restrict__ sMax,
                                               float* __restrict__ Y0,
                                               float* __restrict__ T,
                                               float* __restrict__ Z1) {
  const float inv = 1.0f / __uint_as_float(*sMax);
  const int i0 = (blockIdx.x * 256 + threadIdx.x) * 4;
  const float4 m4 = *(const float4*)&M[i0];
  const int row = i0 >> 9, col0 = i0 & 511;
  float y[4], tv[4];
#pragma unroll
  for (int e = 0; e < 4; ++e) {
    y[e] = (&m4.x)[e] * inv;
    tv[e] = (row == col0 + e ? 1.5f : 0.f) - 0.5f * y[e];
  }
  *(float4*)&Y0[i0] = make_float4(y[0], y[1], y[2], y[3]);
  const float4 t4 = make_float4(tv[0], tv[1], tv[2], tv[3]);
  *(float4*)&T[i0] = t4;
  *(float4*)&Z1[i0] = t4;
}

// ---------------------------------------------------------------------------
// 512x512x512 fp32 matmul body (32x32 tile / block, 2x2 per thread)
// ---------------------------------------------------------------------------
__device__ __forceinline__ void mm512_body(const float* __restrict__ A,
                                           const float* __restrict__ B,
                                           float* a00, float* a01, float* a10,
                                           float* a11, int rbase, int cbase) {
  __shared__ float As[32][36];
  __shared__ float Bs[32][36];
  const int t = threadIdx.x;
  const int tx = t & 15, ty = t >> 4;
  const int sr = t >> 3, sc = (t & 7) * 4;
  float c00 = 0.f, c01 = 0.f, c10 = 0.f, c11 = 0.f;
  for (int k0 = 0; k0 < D; k0 += 32) {
    __syncthreads();
    *(float4*)&As[sr][sc] = *(const float4*)(A + (size_t)(rbase + sr) * D + k0 + sc);
    *(float4*)&Bs[sr][sc] = *(const float4*)(B + (size_t)(k0 + sr) * D + cbase + sc);
    __syncthreads();
#pragma unroll
    for (int kk = 0; kk < 32; ++kk) {
      const float av0 = As[2 * ty][kk], av1 = As[2 * ty + 1][kk];
      const float2 bv = *(const float2*)&Bs[kk][2 * tx];
      c00 = fmaf(av0, bv.x, c00);
      c01 = fmaf(av0, bv.y, c01);
      c10 = fmaf(av1, bv.x, c10);
      c11 = fmaf(av1, bv.y, c11);
    }
  }
  *a00 = c00; *a01 = c01; *a10 = c10; *a11 = c11;
}

// O = A @ B (plain store)
__global__ __launch_bounds__(256) void mmY_k(const float* __restrict__ A,
                                             const float* __restrict__ B,
                                             float* __restrict__ O) {
  const int rbase = blockIdx.y * 32, cbase = blockIdx.x * 32;
  float a00, a01, a10, a11;
  mm512_body(A, B, &a00, &a01, &a10, &a11, rbase, cbase);
  const int tx = threadIdx.x & 15, ty = threadIdx.x >> 4;
  const int r0 = rbase + 2 * ty, c0 = cbase + 2 * tx;
  O[(size_t)r0 * D + c0] = a00;
  O[(size_t)r0 * D + c0 + 1] = a01;
  O[(size_t)(r0 + 1) * D + c0] = a10;
  O[(size_t)(r0 + 1) * D + c0 + 1] = a11;
}

// T = 1.5 I - 0.5 * (Z @ Y)
__global__ __launch_bounds__(256) void mmT_k(const float* __restrict__ Zm,
                                             const float* __restrict__ Ym,
                                             float* __restrict__ T) {
  const int rbase = blockIdx.y * 32, cbase = blockIdx.x * 32;
  float a00, a01, a10, a11;
  mm512_body(Zm, Ym, &a00, &a01, &a10, &a11, rbase, cbase);
  const int tx = threadIdx.x & 15, ty = threadIdx.x >> 4;
  const int r0 = rbase + 2 * ty, c0 = cbase + 2 * tx;
  T[(size_t)r0 * D + c0] = (r0 == c0 ? 1.5f : 0.f) - 0.5f * a00;
  T[(size_t)r0 * D + c0 + 1] = (r0 == c0 + 1 ? 1.5f : 0.f) - 0.5f * a01;
  T[(size_t)(r0 + 1) * D + c0] = (r0 + 1 == c0 ? 1.5f : 0.f) - 0.5f * a10;
  T[(size_t)(r0 + 1) * D + c0 + 1] = (r0 + 1 == c0 + 1 ? 1.5f : 0.f) - 0.5f * a11;
}

// z=0: Ynew = Y @ T ; z=1: Znew = T @ Z
__global__ __launch_bounds__(256) void mmpair_k(const float* __restrict__ Y,
                                                const float* __restrict__ Z,
                                                const float* __restrict__ T,
                                                float* __restrict__ Yn,
                                                float* __restrict__ Zn) {
  const float* A = blockIdx.z ? T : Y;
  const float* B = blockIdx.z ? Z : T;
  float* O = blockIdx.z ? Zn : Yn;
  const int rbase = blockIdx.y * 32, cbase = blockIdx.x * 32;
  float a00, a01, a10, a11;
  mm512_body(A, B, &a00, &a01, &a10, &a11, rbase, cbase);
  const int tx = threadIdx.x & 15, ty = threadIdx.x >> 4;
  const int r0 = rbase + 2 * ty, c0 = cbase + 2 * tx;
  O[(size_t)r0 * D + c0] = a00;
  O[(size_t)r0 * D + c0 + 1] = a01;
  O[(size_t)(r0 + 1) * D + c0] = a10;
  O[(size_t)(r0 + 1) * D + c0 + 1] = a11;
}

// ---------------------------------------------------------------------------
// Kernel 4 (final NS iter, fused): Zfinal = T @ Z, written directly as
// pre-swizzled bf16 panels scaled by 1/sqrt(s).
// panel layout: [nb(4)][ks(8)][nl(128)][ch'(8)][e(8)] bf16  (512 KB)
// ---------------------------------------------------------------------------
__global__ __launch_bounds__(256) void mmZp_k(const float* __restrict__ T,
                                              const float* __restrict__ Z,
                                              const unsigned* __restrict__ sMax,
                                              short* __restrict__ panels) {
  const int rbase = blockIdx.y * 32, cbase = blockIdx.x * 32;
  float a00, a01, a10, a11;
  mm512_body(T, Z, &a00, &a01, &a10, &a11, rbase, cbase);
  const float rs = rsqrtf(__uint_as_float(*sMax));
  const int tx = threadIdx.x & 15, ty = threadIdx.x >> 4;
  const int r0 = rbase + 2 * ty, c0 = cbase + 2 * tx;
  const float vv[2][2] = {{a00, a01}, {a10, a11}};
#pragma unroll
  for (int dr = 0; dr < 2; ++dr)
#pragma unroll
    for (int dc = 0; dc < 2; ++dc) {
      const int k = r0 + dr, n = c0 + dc;
      const int nb_ = n >> 7, nl = n & 127;
      const int ks = k >> 6, kl = k & 63;
      const int ch = (kl >> 3) ^ SWZ8(nl), e = kl & 7;
      const size_t pi = (size_t)((nb_ * 8 + ks) * 128 + nl) * 64 + ch * 8 + e;
      panels[pi] = (short)f2bf(vv[dr][dc] * rs);
    }
}

// ---------------------------------------------------------------------------
// Kernel 5: out = x @ B. grid 8192 (XCD swizzle: 4 ct-sharers co-XCD).
// DOUBLE-BUFFERED DMA pipeline with counted vmcnt: stage t+1 issued at top,
// vmcnt(8) waits only stage t (t+1's 8 DMAs stay in flight across BOTH
// barriers), bottom barrier gates buffer reuse. Epilogue: per-wave LDS
// transpose -> lane-contiguous float4 nontemporal stores.
// ---------------------------------------------------------------------------
__global__ __launch_bounds__(256) void gemm_k(const short* __restrict__ xb16,
                                              const short* __restrict__ panels,
                                              float* __restrict__ out) {
  __shared__ short lds[4][128 * 64];  // [0,1]=A dbuf, [2,3]=B dbuf (64 KB)

  const int hw = blockIdx.x;
  const int q = hw & 7, j = hw >> 3;
  const int ct = j & 3;
  const int rp = ((j >> 2) << 3) | q;
  const size_t rbase = (size_t)rp * 128;

  const int tid = threadIdx.x;
  const int lane = tid & 63, wave = tid >> 6;
  const int wr = wave >> 1, wc = wave & 1;
  const int l15 = lane & 15, g = lane >> 4;
  const int wrow0 = 32 * wave;

  f32x4 acc[4][4];
#pragma unroll
  for (int i = 0; i < 4; ++i)
#pragma unroll
    for (int j2 = 0; j2 < 4; ++j2) acc[i][j2] = f32x4{0.f, 0.f, 0.f, 0.f};

  auto STAGE = [&](int buf, int ksv) {
    // A: 4 DMA issues (source pre-swizzle-XOR'd per lane, LDS linear)
#pragma unroll
    for (int i = 0; i < 4; ++i) {
      const int m = wrow0 + 8 * i + (lane >> 3);
      const short* src = xb16 + (rbase + m) * D + ksv * 64 +
                         (((lane & 7) ^ SWZ8(m)) << 3);
      gld_lds16(src, &lds[buf][(wrow0 + 8 * i) * 64]);
    }
    // B: 4 DMA issues, linear copy of pre-swizzled panel slice
    const short* srcB = panels + ((size_t)(ct * 8 + ksv) << 13);
#pragma unroll
    for (int i = 0; i < 4; ++i)
      gld_lds16(srcB + wave * 2048 + i * 512 + lane * 8,
                &lds[2 + buf][wave * 2048 + i * 512]);
  };

  STAGE(0, 0);  // prologue: 8 DMAs in flight

  for (int ks = 0; ks < 8; ++ks) {
    const int cur = ks & 1;
    if (ks < 7) {
      STAGE(cur ^ 1, ks + 1);  // safe: bottom barrier of ks-1 ended all reads
      asm volatile("s_waitcnt vmcnt(8)" ::: "memory");  // stage ks landed
    } else {
      asm volatile("s_waitcnt vmcnt(0)" ::: "memory");
    }
    __builtin_amdgcn_s_barrier();       // all waves' stage-ks DMAs visible
    __builtin_amdgcn_sched_barrier(0);

    const short* rA = lds[cur];
    const short* rB = lds[2 + cur];
#pragma unroll
    for (int kk = 0; kk < 2; ++kk) {
      s16x8 af[4], bfv[4];
#pragma unroll
      for (int mi = 0; mi < 4; ++mi) {
        const int m = 64 * wr + 16 * mi + l15;
        af[mi] = *(const s16x8*)(rA + m * 64 + ((((kk << 2) | g) ^ SWZ8(m)) << 3));
      }
#pragma unroll
      for (int nj = 0; nj < 4; ++nj) {
        const int n = 64 * wc + 16 * nj + l15;
        bfv[nj] = *(const s16x8*)(rB + n * 64 + ((((kk << 2) | g) ^ SWZ8(n)) << 3));
      }
#pragma unroll
      for (int mi = 0; mi < 4; ++mi)
#pragma unroll
        for (int nj = 0; nj < 4; ++nj)
          acc[mi][nj] = mfma16(af[mi], bfv[nj], acc[mi][nj]);
    }

    // bottom barrier: own ds_reads done (lgkm), then all waves -> next
    // iteration may overwrite buf[cur]. vmcnt NOT drained (t+1 in flight).
    asm volatile("s_waitcnt lgkmcnt(0)" ::: "memory");
    __builtin_amdgcn_s_barrier();
    __builtin_amdgcn_sched_barrier(0);
  }

  // epilogue: per-wave transpose through LDS, then contiguous float4 NT stores
  float* scratch = (float*)&lds[0][0];
  const int wbase = wave * 1088;  // 16 rows x 68 floats per wave
#pragma unroll
  for (int mi = 0; mi < 4; ++mi) {
#pragma unroll
    for (int nj = 0; nj < 4; ++nj)
#pragma unroll
      for (int r = 0; r < 4; ++r)
        scratch[wbase + (4 * g + r) * 68 + 16 * nj + l15] = acc[mi][nj][r];
    __syncthreads();
#pragma unroll
    for (int i = 0; i < 4; ++i) {
      const int rl = g + 4 * i;  // 0..15
      const f32x4 v = *(const f32x4*)&scratch[wbase + rl * 68 + l15 * 4];
      const size_t row_g = rbase + 64 * wr + 16 * mi + rl;
      const int col_g = ct * 128 + 64 * wc + l15 * 4;
      __builtin_nontemporal_store(v, (f32x4*)(out + row_g * D + col_g));
    }
    __syncthreads();
  }
}

// ---------------------------------------------------------------------------
// Fallback (ws too small for xb16): old 2-barrier f2bf gemm from fp32 x.
// ---------------------------------------------------------------------------
__global__ __launch_bounds__(256) void gemm_fb_k(const float* __restrict__ x,
                                                 const short* __restrict__ panels,
                                                 float* __restrict__ out) {
  __shared__ short lds[2 * 128 * 64];
  short* ldsA = lds;
  short* ldsB = lds + 128 * 64;

  const int hw = blockIdx.x;
  const int q = hw & 7, j = hw >> 3;
  const int ct = j & 3;
  const int rp = ((j >> 2) << 3) | q;
  const size_t rbase = (size_t)rp * 128;

  const int tid = threadIdx.x;
  const int lane = tid & 63, wave = tid >> 6;
  const int wr = wave >> 1, wc = wave & 1;
  const int l15 = lane & 15, g = lane >> 4;

  const int mb8 = tid >> 4;
  const int koff = (tid & 15) * 4;
  const int chA = koff >> 3, subA = koff & 7;

  f32x4 acc[4][4];
#pragma unroll
  for (int i = 0; i < 4; ++i)
#pragma unroll
    for (int j2 = 0; j2 < 4; ++j2) acc[i][j2] = f32x4{0.f, 0.f, 0.f, 0.f};

  for (int ks = 0; ks < 8; ++ks) {
    __syncthreads();
#pragma unroll
    for (int i = 0; i < 8; ++i) {
      const int m = mb8 + (i << 4);
      const float4 v = *(const float4*)(x + (rbase + m) * D + ks * 64 + koff);
      s16x4 p;
      p[0] = (short)f2bf(v.x);
      p[1] = (short)f2bf(v.y);
      p[2] = (short)f2bf(v.z);
      p[3] = (short)f2bf(v.w);
      *(s16x4*)(ldsA + m * 64 + ((chA ^ SWZ8(m)) << 3) + subA) = p;
    }
    {
      const short* src = panels + ((size_t)(ct * 8 + ks) << 13);
#pragma unroll
      for (int i = 0; i < 4; ++i)
        gld_lds16(src + wave * 2048 + i * 512 + lane * 8,
                  ldsB + wave * 2048 + i * 512);
    }
    __syncthreads();

#pragma unroll
    for (int kk = 0; kk < 2; ++kk) {
      s16x8 af[4], bfv[4];
#pragma unroll
      for (int mi = 0; mi < 4; ++mi) {
        const int m = 64 * wr + 16 * mi + l15;
        af[mi] = *(const s16x8*)(ldsA + m * 64 + ((((kk << 2) | g) ^ SWZ8(m)) << 3));
      }
#pragma unroll
      for (int nj = 0; nj < 4; ++nj) {
        const int n = 64 * wc + 16 * nj + l15;
        bfv[nj] = *(const s16x8*)(ldsB + n * 64 + ((((kk << 2) | g) ^ SWZ8(n)) << 3));
      }
#pragma unroll
      for (int mi = 0; mi < 4; ++mi)
#pragma unroll
        for (int nj = 0; nj < 4; ++nj)
          acc[mi][nj] = mfma16(af[mi], bfv[nj], acc[mi][nj]);
    }
  }

  __syncthreads();
  float* scratch = (float*)lds;
  const int wbase = wave * 1088;
#pragma unroll
  for (int mi = 0; mi < 4; ++mi) {
#pragma unroll
    for (int nj = 0; nj < 4; ++nj)
#pragma unroll
      for (int r = 0; r < 4; ++r)
        scratch[wbase + (4 * g + r) * 68 + 16 * nj + l15] = acc[mi][nj][r];
    __syncthreads();
#pragma unroll
    for (int i = 0; i < 4; ++i) {
      const int rl = g + 4 * i;
      const f32x4 v = *(const f32x4*)&scratch[wbase + rl * 68 + l15 * 4];
      const size_t row_g = rbase + 64 * wr + 16 * mi + rl;
      const int col_g = ct * 128 + 64 * wc + l15 * 4;
      __builtin_nontemporal_store(v, (f32x4*)(out + row_g * D + col_g));
    }
    __syncthreads();
  }
}

// ---------------------------------------------------------------------------
extern "C" void kernel_launch(void* const* d_in, const int* in_sizes, int n_in,
                              void* d_out, int out_size, void* d_ws,
                              size_t ws_size, hipStream_t stream) {
  (void)in_sizes; (void)n_in; (void)out_size;
  const float* x = (const float*)d_in[0];
  const float* run = (const float*)d_in[1];
  float* out = (float*)d_out;
  uint8_t* ws = (uint8_t*)d_ws;

  float* Cpart = (float*)ws;                          // 8 MB (8 x 1MB)
  unsigned* sMax = (unsigned*)(ws + (8u << 20));      // 256 B slot
  float* M = (float*)(ws + (8u << 20) + 256);         // 1 MB
  float* Ya = M + 262144;
  float* Yb = Ya + 262144;
  float* Za = Yb + 262144;
  float* Zb = Za + 262144;
  float* T = Zb + 262144;
  short* panels = (short*)(T + 262144);               // 512 KB
  short* xb16 = panels + 262144;                      // 256 MB (optional)

  const size_t need =
      (size_t)((uint8_t*)xb16 - ws) + (size_t)N_ROWS * D * sizeof(short);
  const bool big = ws_size >= need;

  (void)hipMemsetAsync(Cpart, 0, (8u << 20) + 256, stream);

  covar_k<<<1280, 256, 0, stream>>>(x, Cpart, big ? xb16 : nullptr);
  prep_k<<<512, 256, 0, stream>>>(Cpart, run, M, sMax);

  // NS iter 1 (Z0 = I): T1 elementwise, Z1 = T1, Y1 = Y0 @ T1
  init2_k<<<256, 256, 0, stream>>>(M, sMax, Ya, T, Za);
  mmY_k<<<dim3(16, 16), 256, 0, stream>>>(Ya, T, Yb);

  // NS iters 2..NS_ITERS-1 (full coupled)
  float *Y = Yb, *Z = Za, *Yn = Ya, *Zn = Zb;
  for (int it = 1; it < NS_ITERS - 1; ++it) {
    mmT_k<<<dim3(16, 16), 256, 0, stream>>>(Z, Y, T);
    mmpair_k<<<dim3(16, 16, 2), 256, 0, stream>>>(Y, Z, T, Yn, Zn);
    float* t1 = Y; Y = Yn; Yn = t1;
    t1 = Z; Z = Zn; Zn = t1;
  }

  // final NS iter: only Z needed; fused panel build
  mmT_k<<<dim3(16, 16), 256, 0, stream>>>(Z, Y, T);
  mmZp_k<<<dim3(16, 16), 256, 0, stream>>>(T, Z, sMax, panels);

  if (big)
    gemm_k<<<8192, 256, 0, stream>>>(xb16, panels, out);
  else
    gemm_fb_k<<<8192, 256, 0, stream>>>(x, panels, out);
}

// Round 11
// 590.199 us; speedup vs baseline: 1.4336x; 1.0346x over previous
//
#include <hip/hip_runtime.h>
#include <stdint.h>

// ---------------------------------------------------------------------------
// BatchWhiten: out = x @ inv_sqrtm(max(0.1*running + 0.9*(x^T x)/N, 1e-5))
// x: [262144, 512] fp32, running: [512,512] fp32, out: [262144,512] fp32
// ---------------------------------------------------------------------------

#define N_ROWS 262144
#define D 512
#define NS_ITERS 3  // 1 simplified (Z0=I) + 1 full + 1 final Z-only (fused)
#define CK_CHUNKS 128
#define CK_ROWS (N_ROWS / CK_CHUNKS)  // 2048
#define BKC 32
#define CK_STEPS (CK_ROWS / BKC)      // 64

typedef float f32x4 __attribute__((ext_vector_type(4)));
typedef short s16x8 __attribute__((ext_vector_type(8)));
typedef short s16x4 __attribute__((ext_vector_type(4)));
typedef __bf16 bf16x8 __attribute__((ext_vector_type(8)));

static __device__ __forceinline__ unsigned short f2bf(float f) {
  unsigned u = __float_as_uint(f);
  u += 0x7FFFu + ((u >> 16) & 1u);  // RNE
  return (unsigned short)(u >> 16);
}

static __device__ __forceinline__ f32x4 mfma16(s16x8 a, s16x8 b, f32x4 c) {
  return __builtin_amdgcn_mfma_f32_16x16x32_bf16(
      __builtin_bit_cast(bf16x8, a), __builtin_bit_cast(bf16x8, b), c, 0, 0, 0);
}

// async global->LDS, 16B per lane; LDS dest = wave-uniform base + lane*16
static __device__ __forceinline__ void gld_lds16(const void* g, void* l) {
  __builtin_amdgcn_global_load_lds(
      (const __attribute__((address_space(1))) void*)g,
      (__attribute__((address_space(3))) void*)l, 16, 0, 0);
}

#define SWZ8(c) (((c) ^ ((c) >> 3)) & 7)

// Conflict-free covar LDS slot map: tile [128 cols][32 k] bf16, 16B slots.
// slot(c,kc) byte-spread: write (64 lanes, fixed kc, c=2*lane{+1}) and all
// fragment reads land 8 lanes per bank-octet — verified balanced.
#define CVOFF(c, kc) \
  ((((c) >> 1) << 6) + ((((((kc) << 1) | ((c) & 1))) ^ SWZ8((c) >> 1)) << 3))

// raw barrier, LDS-writes published, NO vmcnt drain (prefetch spans barrier)
static __device__ __forceinline__ void bar_lgkm() {
  asm volatile("s_waitcnt lgkmcnt(0)" ::: "memory");
  __builtin_amdgcn_s_barrier();
  __builtin_amdgcn_sched_barrier(0);
}

// ---------------------------------------------------------------------------
// Kernel 1: Cpart[xcd] += x^T x (split-K, bf16 MFMA, upper tiles mb<=nb).
// grid 1280 x 512 threads (8 waves). Wave tile 64x32 -> acc = 32 VGPR
// (r10's 64-reg acc capped occupancy at 3 waves/SIMD). Waves 0-3 stage the
// A tile (k-chunk = wave), waves 4-7 stage B. CVOFF mapping kills the
// 16-way ds_write bank conflict (1.887e7, invariant r7-r10). Register
// prefetch + LDS dbuf + lgkm-only barrier (no vmcnt drain) kept from r10.
// xb16 dump: tile's 4 stager-works (ranks 0..3) each dump their k-chunk.
// ---------------------------------------------------------------------------
__global__ __launch_bounds__(512) void covar_k(const float* __restrict__ x,
                                               float* __restrict__ Cpart,
                                               short* __restrict__ xb16) {
  __shared__ short ldsT[2][2][128 * 32];  // [dbuf][A,B][tile] = 32 KB

  // bijective XCD swizzle: 1280 works = 8 XCDs x 160
  const int hw = blockIdx.x;
  const int work = (hw & 7) * 160 + (hw >> 3);
  int t = work % 10, mb = 0, rl = 4;
  while (t >= rl) { t -= rl; ++mb; --rl; }
  const int nb = mb + t;
  const int chunk = work / 10;
  float* C = Cpart + (size_t)(hw & 7) * (D * D);

  const int tid = threadIdx.x;
  const int lane = tid & 63;
  const int wave = tid >> 6;   // 0..7
  const int isB = wave >> 2;   // staging role: 0 = A tile, 1 = B tile
  const int kh = wave & 3;     // staged k-chunk (8 rows)
  const int c2 = lane * 2;     // staged column pair

  const int wr = wave >> 2, wc = wave & 3;  // MFMA wave tile 64(m) x 32(n)
  const int l15 = lane & 15, g = lane >> 4;

  const bool offd = (nb != mb);
  const bool doStage = (!isB) || offd;  // diag: B-waves don't stage
  const int tileCol = (isB ? nb : mb) * 128;

  const bool haveDump = (xb16 != nullptr);
  const int rank = isB ? (4 - (nb - mb)) : (nb - mb);
  const bool dump = haveDump && doStage && (kh == rank);
  uint32_t* xw = (uint32_t*)xb16;

  f32x4 acc[4][2];
#pragma unroll
  for (int i = 0; i < 4; ++i)
#pragma unroll
    for (int j = 0; j < 2; ++j) acc[i][j] = f32x4{0.f, 0.f, 0.f, 0.f};

  const size_t kbase0 = (size_t)chunk * CK_ROWS;
  const float* srcBase = x + (kbase0 + kh * 8) * D + tileCol + c2;

  // register prefetch (16 VGPR)
  float2 buf[8];
  if (doStage) {
#pragma unroll
    for (int q = 0; q < 8; ++q) buf[q] = *(const float2*)(srcBase + (size_t)q * D);
  }

  for (int st = 0; st < CK_STEPS; ++st) {
    if (doStage) {
      // convert landed loads to bf16
      s16x8 p0, p1;
#pragma unroll
      for (int q = 0; q < 8; ++q) {
        p0[q] = (short)f2bf(buf[q].x);
        p1[q] = (short)f2bf(buf[q].y);
      }
      // issue next step's loads (latency spans the lgkm-only barrier + MFMA)
      if (st + 1 < CK_STEPS) {
        const float* src = srcBase + (size_t)(st + 1) * BKC * D;
#pragma unroll
        for (int q = 0; q < 8; ++q) buf[q] = *(const float2*)(src + (size_t)q * D);
      }
      // conflict-free LDS write
      short* wp = ldsT[st & 1][isB];
      *(s16x8*)(wp + CVOFF(c2, kh)) = p0;
      *(s16x8*)(wp + CVOFF(c2 + 1, kh)) = p1;
      if (dump) {
        const size_t k0 = kbase0 + (size_t)st * BKC;
#pragma unroll
        for (int q = 0; q < 8; ++q) {
          const uint32_t u =
              (uint32_t)(uint16_t)p0[q] | ((uint32_t)(uint16_t)p1[q] << 16);
          __builtin_nontemporal_store(
              u, &xw[(k0 + kh * 8 + q) * 256 + (tileCol >> 1) + lane]);
        }
      }
    }

    bar_lgkm();  // publish ds_writes; NO vmcnt drain

    const short* rA = ldsT[st & 1][0];
    const short* rB = ldsT[st & 1][offd ? 1 : 0];
    s16x8 af[4], bfv[2];
#pragma unroll
    for (int mi = 0; mi < 4; ++mi) {
      const int m = 64 * wr + 16 * mi + l15;
      af[mi] = *(const s16x8*)(rA + CVOFF(m, g));
    }
#pragma unroll
    for (int nj = 0; nj < 2; ++nj) {
      const int n = 32 * wc + 16 * nj + l15;
      bfv[nj] = *(const s16x8*)(rB + CVOFF(n, g));
    }
#pragma unroll
    for (int mi = 0; mi < 4; ++mi)
#pragma unroll
      for (int nj = 0; nj < 2; ++nj)
        acc[mi][nj] = mfma16(af[mi], bfv[nj], acc[mi][nj]);
  }

  // epilogue: atomic accumulate into this XCD's partial buffer
#pragma unroll
  for (int mi = 0; mi < 4; ++mi)
#pragma unroll
    for (int nj = 0; nj < 2; ++nj) {
      const int n = nb * 128 + 32 * wc + 16 * nj + l15;
#pragma unroll
      for (int r = 0; r < 4; ++r) {
        const int m = mb * 128 + 64 * wr + 16 * mi + 4 * g + r;
        atomicAdd(&C[(size_t)m * D + n], acc[mi][nj][r]);
      }
    }
}

// ---------------------------------------------------------------------------
// Kernel 2: M = max(0.1*run + (0.9/N)*sum_p Cpart[p], 1e-5); sMax = max rowsum
// ---------------------------------------------------------------------------
__global__ __launch_bounds__(256) void prep_k(const float* __restrict__ Cpart,
                                              const float* __restrict__ run,
                                              float* __restrict__ M,
                                              unsigned* __restrict__ sMax) {
  const int r = blockIdx.x;
  const int t = threadIdx.x;
  const float cs = 0.9f / (float)N_ROWS;
  float sum = 0.f;
  for (int c = t; c < D; c += 256) {
    const int rr = r < c ? r : c;
    const int cc = r < c ? c : r;
    float cv = 0.f;
#pragma unroll
    for (int p = 0; p < 8; ++p)
      cv += Cpart[(size_t)p * D * D + (size_t)rr * D + cc];
    float v = 0.1f * run[(size_t)r * D + c] + cs * cv;
    v = fmaxf(v, 1e-5f);
    M[(size_t)r * D + c] = v;
    sum += v;  // all entries positive after clamp
  }
  __shared__ float red[256];
  red[t] = sum;
  __syncthreads();
  for (int off = 128; off > 0; off >>= 1) {
    if (t < off) red[t] += red[t + off];
    __syncthreads();
  }
  if (t == 0) atomicMax(sMax, __float_as_uint(red[0]));
}

// ---------------------------------------------------------------------------
// Kernel 3: iter-1 shortcut. Y0 = M/s; T1 = 1.5I - 0.5*Y0; Z1 = T1.
// ---------------------------------------------------------------------------
__global__ __launch_bounds__(256) void init2_k(const float* __restrict__ M,
                                               const unsigned* __restrict__ sMax,
                                               float* __restrict__ Y0,
                                               float* __restrict__ T,
                                               float* __restrict__ Z1) {
  const float inv = 1.0f / __uint_as_float(*sMax);
  const int i0 = (blockIdx.x * 256 + threadIdx.x) * 4;
  const float4 m4 = *(const float4*)&M[i0];
  const int row = i0 >> 9, col0 = i0 & 511;
  float y[4], tv[4];
#pragma unroll
  for (int e = 0; e < 4; ++e) {
    y[e] = (&m4.x)[e] * inv;
    tv[e] = (row == col0 + e ? 1.5f : 0.f) - 0.5f * y[e];
  }
  *(float4*)&Y0[i0] = make_float4(y[0], y[1], y[2], y[3]);
  const float4 t4 = make_float4(tv[0], tv[1], tv[2], tv[3]);
  *(float4*)&T[i0] = t4;
  *(float4*)&Z1[i0] = t4;
}

// ---------------------------------------------------------------------------
// 512x512x512 fp32 matmul body (32x32 tile / block, 2x2 per thread)
// ---------------------------------------------------------------------------
__device__ __forceinline__ void mm512_body(const float* __restrict__ A,
                                           const float* __restrict__ B,
                                           float* a00, float* a01, float* a10,
                                           float* a11, int rbase, int cbase) {
  __shared__ float As[32][36];
  __shared__ float Bs[32][36];
  const int t = threadIdx.x;
  const int tx = t & 15, ty = t >> 4;
  const int sr = t >> 3, sc = (t & 7) * 4;
  float c00 = 0.f, c01 = 0.f, c10 = 0.f, c11 = 0.f;
  for (int k0 = 0; k0 < D; k0 += 32) {
    __syncthreads();
    *(float4*)&As[sr][sc] = *(const float4*)(A + (size_t)(rbase + sr) * D + k0 + sc);
    *(float4*)&Bs[sr][sc] = *(const float4*)(B + (size_t)(k0 + sr) * D + cbase + sc);
    __syncthreads();
#pragma unroll
    for (int kk = 0; kk < 32; ++kk) {
      const float av0 = As[2 * ty][kk], av1 = As[2 * ty + 1][kk];
      const float2 bv = *(const float2*)&Bs[kk][2 * tx];
      c00 = fmaf(av0, bv.x, c00);
      c01 = fmaf(av0, bv.y, c01);
      c10 = fmaf(av1, bv.x, c10);
      c11 = fmaf(av1, bv.y, c11);
    }
  }
  *a00 = c00; *a01 = c01; *a10 = c10; *a11 = c11;
}

// O = A @ B (plain store)
__global__ __launch_bounds__(256) void mmY_k(const float* __restrict__ A,
                                             const float* __restrict__ B,
                                             float* __restrict__ O) {
  const int rbase = blockIdx.y * 32, cbase = blockIdx.x * 32;
  float a00, a01, a10, a11;
  mm512_body(A, B, &a00, &a01, &a10, &a11, rbase, cbase);
  const int tx = threadIdx.x & 15, ty = threadIdx.x >> 4;
  const int r0 = rbase + 2 * ty, c0 = cbase + 2 * tx;
  O[(size_t)r0 * D + c0] = a00;
  O[(size_t)r0 * D + c0 + 1] = a01;
  O[(size_t)(r0 + 1) * D + c0] = a10;
  O[(size_t)(r0 + 1) * D + c0 + 1] = a11;
}

// T = 1.5 I - 0.5 * (Z @ Y)
__global__ __launch_bounds__(256) void mmT_k(const float* __restrict__ Zm,
                                             const float* __restrict__ Ym,
                                             float* __restrict__ T) {
  const int rbase = blockIdx.y * 32, cbase = blockIdx.x * 32;
  float a00, a01, a10, a11;
  mm512_body(Zm, Ym, &a00, &a01, &a10, &a11, rbase, cbase);
  const int tx = threadIdx.x & 15, ty = threadIdx.x >> 4;
  const int r0 = rbase + 2 * ty, c0 = cbase + 2 * tx;
  T[(size_t)r0 * D + c0] = (r0 == c0 ? 1.5f : 0.f) - 0.5f * a00;
  T[(size_t)r0 * D + c0 + 1] = (r0 == c0 + 1 ? 1.5f : 0.f) - 0.5f * a01;
  T[(size_t)(r0 + 1) * D + c0] = (r0 + 1 == c0 ? 1.5f : 0.f) - 0.5f * a10;
  T[(size_t)(r0 + 1) * D + c0 + 1] = (r0 + 1 == c0 + 1 ? 1.5f : 0.f) - 0.5f * a11;
}

// z=0: Ynew = Y @ T ; z=1: Znew = T @ Z
__global__ __launch_bounds__(256) void mmpair_k(const float* __restrict__ Y,
                                                const float* __restrict__ Z,
                                                const float* __restrict__ T,
                                                float* __restrict__ Yn,
                                                float* __restrict__ Zn) {
  const float* A = blockIdx.z ? T : Y;
  const float* B = blockIdx.z ? Z : T;
  float* O = blockIdx.z ? Zn : Yn;
  const int rbase = blockIdx.y * 32, cbase = blockIdx.x * 32;
  float a00, a01, a10, a11;
  mm512_body(A, B, &a00, &a01, &a10, &a11, rbase, cbase);
  const int tx = threadIdx.x & 15, ty = threadIdx.x >> 4;
  const int r0 = rbase + 2 * ty, c0 = cbase + 2 * tx;
  O[(size_t)r0 * D + c0] = a00;
  O[(size_t)r0 * D + c0 + 1] = a01;
  O[(size_t)(r0 + 1) * D + c0] = a10;
  O[(size_t)(r0 + 1) * D + c0 + 1] = a11;
}

// ---------------------------------------------------------------------------
// Kernel 4 (final NS iter, fused): Zfinal = T @ Z, written directly as
// pre-swizzled bf16 panels scaled by 1/sqrt(s).
// panel layout: [nb(4)][ks(8)][nl(128)][ch'(8)][e(8)] bf16  (512 KB)
// ---------------------------------------------------------------------------
__global__ __launch_bounds__(256) void mmZp_k(const float* __restrict__ T,
                                              const float* __restrict__ Z,
                                              const unsigned* __restrict__ sMax,
                                              short* __restrict__ panels) {
  const int rbase = blockIdx.y * 32, cbase = blockIdx.x * 32;
  float a00, a01, a10, a11;
  mm512_body(T, Z, &a00, &a01, &a10, &a11, rbase, cbase);
  const float rs = rsqrtf(__uint_as_float(*sMax));
  const int tx = threadIdx.x & 15, ty = threadIdx.x >> 4;
  const int r0 = rbase + 2 * ty, c0 = cbase + 2 * tx;
  const float vv[2][2] = {{a00, a01}, {a10, a11}};
#pragma unroll
  for (int dr = 0; dr < 2; ++dr)
#pragma unroll
    for (int dc = 0; dc < 2; ++dc) {
      const int k = r0 + dr, n = c0 + dc;
      const int nb_ = n >> 7, nl = n & 127;
      const int ks = k >> 6, kl = k & 63;
      const int ch = (kl >> 3) ^ SWZ8(nl), e = kl & 7;
      const size_t pi = (size_t)((nb_ * 8 + ks) * 128 + nl) * 64 + ch * 8 + e;
      panels[pi] = (short)f2bf(vv[dr][dc] * rs);
    }
}

// ---------------------------------------------------------------------------
// Kernel 5: out = x @ B. grid 8192 (XCD swizzle: 4 ct-sharers co-XCD).
// Double-buffered DMA pipeline with counted vmcnt (r10, kept).
// ---------------------------------------------------------------------------
__global__ __launch_bounds__(256) void gemm_k(const short* __restrict__ xb16,
                                              const short* __restrict__ panels,
                                              float* __restrict__ out) {
  __shared__ short lds[4][128 * 64];  // [0,1]=A dbuf, [2,3]=B dbuf (64 KB)

  const int hw = blockIdx.x;
  const int q = hw & 7, j = hw >> 3;
  const int ct = j & 3;
  const int rp = ((j >> 2) << 3) | q;
  const size_t rbase = (size_t)rp * 128;

  const int tid = threadIdx.x;
  const int lane = tid & 63, wave = tid >> 6;
  const int wr = wave >> 1, wc = wave & 1;
  const int l15 = lane & 15, g = lane >> 4;
  const int wrow0 = 32 * wave;

  f32x4 acc[4][4];
#pragma unroll
  for (int i = 0; i < 4; ++i)
#pragma unroll
    for (int j2 = 0; j2 < 4; ++j2) acc[i][j2] = f32x4{0.f, 0.f, 0.f, 0.f};

  auto STAGE = [&](int buf, int ksv) {
#pragma unroll
    for (int i = 0; i < 4; ++i) {
      const int m = wrow0 + 8 * i + (lane >> 3);
      const short* src = xb16 + (rbase + m) * D + ksv * 64 +
                         (((lane & 7) ^ SWZ8(m)) << 3);
      gld_lds16(src, &lds[buf][(wrow0 + 8 * i) * 64]);
    }
    const short* srcB = panels + ((size_t)(ct * 8 + ksv) << 13);
#pragma unroll
    for (int i = 0; i < 4; ++i)
      gld_lds16(srcB + wave * 2048 + i * 512 + lane * 8,
                &lds[2 + buf][wave * 2048 + i * 512]);
  };

  STAGE(0, 0);  // prologue: 8 DMAs in flight

  for (int ks = 0; ks < 8; ++ks) {
    const int cur = ks & 1;
    if (ks < 7) {
      STAGE(cur ^ 1, ks + 1);
      asm volatile("s_waitcnt vmcnt(8)" ::: "memory");  // stage ks landed
    } else {
      asm volatile("s_waitcnt vmcnt(0)" ::: "memory");
    }
    __builtin_amdgcn_s_barrier();
    __builtin_amdgcn_sched_barrier(0);

    const short* rA = lds[cur];
    const short* rB = lds[2 + cur];
#pragma unroll
    for (int kk = 0; kk < 2; ++kk) {
      s16x8 af[4], bfv[4];
#pragma unroll
      for (int mi = 0; mi < 4; ++mi) {
        const int m = 64 * wr + 16 * mi + l15;
        af[mi] = *(const s16x8*)(rA + m * 64 + ((((kk << 2) | g) ^ SWZ8(m)) << 3));
      }
#pragma unroll
      for (int nj = 0; nj < 4; ++nj) {
        const int n = 64 * wc + 16 * nj + l15;
        bfv[nj] = *(const s16x8*)(rB + n * 64 + ((((kk << 2) | g) ^ SWZ8(n)) << 3));
      }
#pragma unroll
      for (int mi = 0; mi < 4; ++mi)
#pragma unroll
        for (int nj = 0; nj < 4; ++nj)
          acc[mi][nj] = mfma16(af[mi], bfv[nj], acc[mi][nj]);
    }

    asm volatile("s_waitcnt lgkmcnt(0)" ::: "memory");
    __builtin_amdgcn_s_barrier();
    __builtin_amdgcn_sched_barrier(0);
  }

  // epilogue: per-wave transpose through LDS, then contiguous float4 NT stores
  float* scratch = (float*)&lds[0][0];
  const int wbase = wave * 1088;  // 16 rows x 68 floats per wave
#pragma unroll
  for (int mi = 0; mi < 4; ++mi) {
#pragma unroll
    for (int nj = 0; nj < 4; ++nj)
#pragma unroll
      for (int r = 0; r < 4; ++r)
        scratch[wbase + (4 * g + r) * 68 + 16 * nj + l15] = acc[mi][nj][r];
    __syncthreads();
#pragma unroll
    for (int i = 0; i < 4; ++i) {
      const int rl = g + 4 * i;  // 0..15
      const f32x4 v = *(const f32x4*)&scratch[wbase + rl * 68 + l15 * 4];
      const size_t row_g = rbase + 64 * wr + 16 * mi + rl;
      const int col_g = ct * 128 + 64 * wc + l15 * 4;
      __builtin_nontemporal_store(v, (f32x4*)(out + row_g * D + col_g));
    }
    __syncthreads();
  }
}

// ---------------------------------------------------------------------------
// Fallback (ws too small for xb16): old 2-barrier f2bf gemm from fp32 x.
// ---------------------------------------------------------------------------
__global__ __launch_bounds__(256) void gemm_fb_k(const float* __restrict__ x,
                                                 const short* __restrict__ panels,
                                                 float* __restrict__ out) {
  __shared__ short lds[2 * 128 * 64];
  short* ldsA = lds;
  short* ldsB = lds + 128 * 64;

  const int hw = blockIdx.x;
  const int q = hw & 7, j = hw >> 3;
  const int ct = j & 3;
  const int rp = ((j >> 2) << 3) | q;
  const size_t rbase = (size_t)rp * 128;

  const int tid = threadIdx.x;
  const int lane = tid & 63, wave = tid >> 6;
  const int wr = wave >> 1, wc = wave & 1;
  const int l15 = lane & 15, g = lane >> 4;

  const int mb8 = tid >> 4;
  const int koff = (tid & 15) * 4;
  const int chA = koff >> 3, subA = koff & 7;

  f32x4 acc[4][4];
#pragma unroll
  for (int i = 0; i < 4; ++i)
#pragma unroll
    for (int j2 = 0; j2 < 4; ++j2) acc[i][j2] = f32x4{0.f, 0.f, 0.f, 0.f};

  for (int ks = 0; ks < 8; ++ks) {
    __syncthreads();
#pragma unroll
    for (int i = 0; i < 8; ++i) {
      const int m = mb8 + (i << 4);
      const float4 v = *(const float4*)(x + (rbase + m) * D + ks * 64 + koff);
      s16x4 p;
      p[0] = (short)f2bf(v.x);
      p[1] = (short)f2bf(v.y);
      p[2] = (short)f2bf(v.z);
      p[3] = (short)f2bf(v.w);
      *(s16x4*)(ldsA + m * 64 + ((chA ^ SWZ8(m)) << 3) + subA) = p;
    }
    {
      const short* src = panels + ((size_t)(ct * 8 + ks) << 13);
#pragma unroll
      for (int i = 0; i < 4; ++i)
        gld_lds16(src + wave * 2048 + i * 512 + lane * 8,
                  ldsB + wave * 2048 + i * 512);
    }
    __syncthreads();

#pragma unroll
    for (int kk = 0; kk < 2; ++kk) {
      s16x8 af[4], bfv[4];
#pragma unroll
      for (int mi = 0; mi < 4; ++mi) {
        const int m = 64 * wr + 16 * mi + l15;
        af[mi] = *(const s16x8*)(ldsA + m * 64 + ((((kk << 2) | g) ^ SWZ8(m)) << 3));
      }
#pragma unroll
      for (int nj = 0; nj < 4; ++nj) {
        const int n = 64 * wc + 16 * nj + l15;
        bfv[nj] = *(const s16x8*)(ldsB + n * 64 + ((((kk << 2) | g) ^ SWZ8(n)) << 3));
      }
#pragma unroll
      for (int mi = 0; mi < 4; ++mi)
#pragma unroll
        for (int nj = 0; nj < 4; ++nj)
          acc[mi][nj] = mfma16(af[mi], bfv[nj], acc[mi][nj]);
    }
  }

  __syncthreads();
  float* scratch = (float*)lds;
  const int wbase = wave * 1088;
#pragma unroll
  for (int mi = 0; mi < 4; ++mi) {
#pragma unroll
    for (int nj = 0; nj < 4; ++nj)
#pragma unroll
      for (int r = 0; r < 4; ++r)
        scratch[wbase + (4 * g + r) * 68 + 16 * nj + l15] = acc[mi][nj][r];
    __syncthreads();
#pragma unroll
    for (int i = 0; i < 4; ++i) {
      const int rl = g + 4 * i;
      const f32x4 v = *(const f32x4*)&scratch[wbase + rl * 68 + l15 * 4];
      const size_t row_g = rbase + 64 * wr + 16 * mi + rl;
      const int col_g = ct * 128 + 64 * wc + l15 * 4;
      __builtin_nontemporal_store(v, (f32x4*)(out + row_g * D + col_g));
    }
    __syncthreads();
  }
}

// ---------------------------------------------------------------------------
extern "C" void kernel_launch(void* const* d_in, const int* in_sizes, int n_in,
                              void* d_out, int out_size, void* d_ws,
                              size_t ws_size, hipStream_t stream) {
  (void)in_sizes; (void)n_in; (void)out_size;
  const float* x = (const float*)d_in[0];
  const float* run = (const float*)d_in[1];
  float* out = (float*)d_out;
  uint8_t* ws = (uint8_t*)d_ws;

  float* Cpart = (float*)ws;                          // 8 MB (8 x 1MB)
  unsigned* sMax = (unsigned*)(ws + (8u << 20));      // 256 B slot
  float* M = (float*)(ws + (8u << 20) + 256);         // 1 MB
  float* Ya = M + 262144;
  float* Yb = Ya + 262144;
  float* Za = Yb + 262144;
  float* Zb = Za + 262144;
  float* T = Zb + 262144;
  short* panels = (short*)(T + 262144);               // 512 KB
  short* xb16 = panels + 262144;                      // 256 MB (optional)

  const size_t need =
      (size_t)((uint8_t*)xb16 - ws) + (size_t)N_ROWS * D * sizeof(short);
  const bool big = ws_size >= need;

  (void)hipMemsetAsync(Cpart, 0, (8u << 20) + 256, stream);

  covar_k<<<1280, 512, 0, stream>>>(x, Cpart, big ? xb16 : nullptr);
  prep_k<<<512, 256, 0, stream>>>(Cpart, run, M, sMax);

  // NS iter 1 (Z0 = I): T1 elementwise, Z1 = T1, Y1 = Y0 @ T1
  init2_k<<<256, 256, 0, stream>>>(M, sMax, Ya, T, Za);
  mmY_k<<<dim3(16, 16), 256, 0, stream>>>(Ya, T, Yb);

  // NS iters 2..NS_ITERS-1 (full coupled)
  float *Y = Yb, *Z = Za, *Yn = Ya, *Zn = Zb;
  for (int it = 1; it < NS_ITERS - 1; ++it) {
    mmT_k<<<dim3(16, 16), 256, 0, stream>>>(Z, Y, T);
    mmpair_k<<<dim3(16, 16, 2), 256, 0, stream>>>(Y, Z, T, Yn, Zn);
    float* t1 = Y; Y = Yn; Yn = t1;
    t1 = Z; Z = Zn; Zn = t1;
  }

  // final NS iter: only Z needed; fused panel build
  mmT_k<<<dim3(16, 16), 256, 0, stream>>>(Z, Y, T);
  mmZp_k<<<dim3(16, 16), 256, 0, stream>>>(T, Z, sMax, panels);

  if (big)
    gemm_k<<<8192, 256, 0, stream>>>(xb16, panels, out);
  else
    gemm_fb_k<<<8192, 256, 0, stream>>>(x, panels, out);
}

// Round 12
// 561.750 us; speedup vs baseline: 1.5062x; 1.0506x over previous
//
#include <hip/hip_runtime.h>
#include <stdint.h>

// ---------------------------------------------------------------------------
// BatchWhiten: out = x @ inv_sqrtm(max(0.1*running + 0.9*(x^T x)/N, 1e-5))
// x: [262144, 512] fp32, running: [512,512] fp32, out: [262144,512] fp32
// ---------------------------------------------------------------------------

#define N_ROWS 262144
#define D 512
#define NS_ITERS 3  // 1 simplified (Z0=I) + 1 full + 1 final Z-only (fused)
#define CK_CHUNKS 128
#define CK_ROWS (N_ROWS / CK_CHUNKS)  // 2048
#define BKC 32
#define CK_STEPS (CK_ROWS / BKC)      // 64

typedef float f32x4 __attribute__((ext_vector_type(4)));
typedef short s16x8 __attribute__((ext_vector_type(8)));
typedef short s16x4 __attribute__((ext_vector_type(4)));
typedef __bf16 bf16x8 __attribute__((ext_vector_type(8)));

static __device__ __forceinline__ unsigned short f2bf(float f) {
  unsigned u = __float_as_uint(f);
  u += 0x7FFFu + ((u >> 16) & 1u);  // RNE
  return (unsigned short)(u >> 16);
}

static __device__ __forceinline__ f32x4 mfma16(s16x8 a, s16x8 b, f32x4 c) {
  return __builtin_amdgcn_mfma_f32_16x16x32_bf16(
      __builtin_bit_cast(bf16x8, a), __builtin_bit_cast(bf16x8, b), c, 0, 0, 0);
}

// async global->LDS, 16B per lane; LDS dest = wave-uniform base + lane*16
static __device__ __forceinline__ void gld_lds16(const void* g, void* l) {
  __builtin_amdgcn_global_load_lds(
      (const __attribute__((address_space(1))) void*)g,
      (__attribute__((address_space(3))) void*)l, 16, 0, 0);
}

#define SWZ8(c) (((c) ^ ((c) >> 3)) & 7)

// Conflict-free covar LDS slot map (r11, verified): tile [128 c][32 k] bf16.
#define CVOFF(c, kc) \
  ((((c) >> 1) << 6) + ((((((kc) << 1) | ((c) & 1))) ^ SWZ8((c) >> 1)) << 3))

// BK=32 row swizzle for gemm tiles (rows = 32 shorts = 64B):
// chunk' = g ^ ((row>>1)&3). Bijective onto each 16-row x 1KB span ->
// fragment reads are full-coverage (conflict-free).
#define GSW(row, g) (((g) ^ (((row) >> 1) & 3)) << 3)

// raw barrier, LDS-writes published, NO vmcnt drain
static __device__ __forceinline__ void bar_lgkm() {
  asm volatile("s_waitcnt lgkmcnt(0)" ::: "memory");
  __builtin_amdgcn_s_barrier();
  __builtin_amdgcn_sched_barrier(0);
}

// ---------------------------------------------------------------------------
// Kernel 1 (r11, kept): Cpart[xcd] += x^T x. grid 1280 x 512 thr.
// ---------------------------------------------------------------------------
__global__ __launch_bounds__(512) void covar_k(const float* __restrict__ x,
                                               float* __restrict__ Cpart,
                                               short* __restrict__ xb16) {
  __shared__ short ldsT[2][2][128 * 32];  // [dbuf][A,B][tile] = 32 KB

  const int hw = blockIdx.x;
  const int work = (hw & 7) * 160 + (hw >> 3);
  int t = work % 10, mb = 0, rl = 4;
  while (t >= rl) { t -= rl; ++mb; --rl; }
  const int nb = mb + t;
  const int chunk = work / 10;
  float* C = Cpart + (size_t)(hw & 7) * (D * D);

  const int tid = threadIdx.x;
  const int lane = tid & 63;
  const int wave = tid >> 6;   // 0..7
  const int isB = wave >> 2;   // staging role: 0 = A tile, 1 = B tile
  const int kh = wave & 3;     // staged k-chunk (8 rows)
  const int c2 = lane * 2;     // staged column pair

  const int wr = wave >> 2, wc = wave & 3;  // MFMA wave tile 64(m) x 32(n)
  const int l15 = lane & 15, g = lane >> 4;

  const bool offd = (nb != mb);
  const bool doStage = (!isB) || offd;
  const int tileCol = (isB ? nb : mb) * 128;

  const bool haveDump = (xb16 != nullptr);
  const int rank = isB ? (4 - (nb - mb)) : (nb - mb);
  const bool dump = haveDump && doStage && (kh == rank);
  uint32_t* xw = (uint32_t*)xb16;

  f32x4 acc[4][2];
#pragma unroll
  for (int i = 0; i < 4; ++i)
#pragma unroll
    for (int j = 0; j < 2; ++j) acc[i][j] = f32x4{0.f, 0.f, 0.f, 0.f};

  const size_t kbase0 = (size_t)chunk * CK_ROWS;
  const float* srcBase = x + (kbase0 + kh * 8) * D + tileCol + c2;

  float2 buf[8];
  if (doStage) {
#pragma unroll
    for (int q = 0; q < 8; ++q) buf[q] = *(const float2*)(srcBase + (size_t)q * D);
  }

  for (int st = 0; st < CK_STEPS; ++st) {
    if (doStage) {
      s16x8 p0, p1;
#pragma unroll
      for (int q = 0; q < 8; ++q) {
        p0[q] = (short)f2bf(buf[q].x);
        p1[q] = (short)f2bf(buf[q].y);
      }
      if (st + 1 < CK_STEPS) {
        const float* src = srcBase + (size_t)(st + 1) * BKC * D;
#pragma unroll
        for (int q = 0; q < 8; ++q) buf[q] = *(const float2*)(src + (size_t)q * D);
      }
      short* wp = ldsT[st & 1][isB];
      *(s16x8*)(wp + CVOFF(c2, kh)) = p0;
      *(s16x8*)(wp + CVOFF(c2 + 1, kh)) = p1;
      if (dump) {
        const size_t k0 = kbase0 + (size_t)st * BKC;
#pragma unroll
        for (int q = 0; q < 8; ++q) {
          const uint32_t u =
              (uint32_t)(uint16_t)p0[q] | ((uint32_t)(uint16_t)p1[q] << 16);
          __builtin_nontemporal_store(
              u, &xw[(k0 + kh * 8 + q) * 256 + (tileCol >> 1) + lane]);
        }
      }
    }

    bar_lgkm();

    const short* rA = ldsT[st & 1][0];
    const short* rB = ldsT[st & 1][offd ? 1 : 0];
    s16x8 af[4], bfv[2];
#pragma unroll
    for (int mi = 0; mi < 4; ++mi) {
      const int m = 64 * wr + 16 * mi + l15;
      af[mi] = *(const s16x8*)(rA + CVOFF(m, g));
    }
#pragma unroll
    for (int nj = 0; nj < 2; ++nj) {
      const int n = 32 * wc + 16 * nj + l15;
      bfv[nj] = *(const s16x8*)(rB + CVOFF(n, g));
    }
#pragma unroll
    for (int mi = 0; mi < 4; ++mi)
#pragma unroll
      for (int nj = 0; nj < 2; ++nj)
        acc[mi][nj] = mfma16(af[mi], bfv[nj], acc[mi][nj]);
  }

#pragma unroll
  for (int mi = 0; mi < 4; ++mi)
#pragma unroll
    for (int nj = 0; nj < 2; ++nj) {
      const int n = nb * 128 + 32 * wc + 16 * nj + l15;
#pragma unroll
      for (int r = 0; r < 4; ++r) {
        const int m = mb * 128 + 64 * wr + 16 * mi + 4 * g + r;
        atomicAdd(&C[(size_t)m * D + n], acc[mi][nj][r]);
      }
    }
}

// ---------------------------------------------------------------------------
// Kernel 2: M = max(0.1*run + (0.9/N)*sum_p Cpart[p], 1e-5); sMax = max rowsum
// ---------------------------------------------------------------------------
__global__ __launch_bounds__(256) void prep_k(const float* __restrict__ Cpart,
                                              const float* __restrict__ run,
                                              float* __restrict__ M,
                                              unsigned* __restrict__ sMax) {
  const int r = blockIdx.x;
  const int t = threadIdx.x;
  const float cs = 0.9f / (float)N_ROWS;
  float sum = 0.f;
  for (int c = t; c < D; c += 256) {
    const int rr = r < c ? r : c;
    const int cc = r < c ? c : r;
    float cv = 0.f;
#pragma unroll
    for (int p = 0; p < 8; ++p)
      cv += Cpart[(size_t)p * D * D + (size_t)rr * D + cc];
    float v = 0.1f * run[(size_t)r * D + c] + cs * cv;
    v = fmaxf(v, 1e-5f);
    M[(size_t)r * D + c] = v;
    sum += v;
  }
  __shared__ float red[256];
  red[t] = sum;
  __syncthreads();
  for (int off = 128; off > 0; off >>= 1) {
    if (t < off) red[t] += red[t + off];
    __syncthreads();
  }
  if (t == 0) atomicMax(sMax, __float_as_uint(red[0]));
}

// ---------------------------------------------------------------------------
// Kernel 3: iter-1 shortcut. Y0 = M/s; T1 = 1.5I - 0.5*Y0; Z1 = T1.
// ---------------------------------------------------------------------------
__global__ __launch_bounds__(256) void init2_k(const float* __restrict__ M,
                                               const unsigned* __restrict__ sMax,
                                               float* __restrict__ Y0,
                                               float* __restrict__ T,
                                               float* __restrict__ Z1) {
  const float inv = 1.0f / __uint_as_float(*sMax);
  const int i0 = (blockIdx.x * 256 + threadIdx.x) * 4;
  const float4 m4 = *(const float4*)&M[i0];
  const int row = i0 >> 9, col0 = i0 & 511;
  float y[4], tv[4];
#pragma unroll
  for (int e = 0; e < 4; ++e) {
    y[e] = (&m4.x)[e] * inv;
    tv[e] = (row == col0 + e ? 1.5f : 0.f) - 0.5f * y[e];
  }
  *(float4*)&Y0[i0] = make_float4(y[0], y[1], y[2], y[3]);
  const float4 t4 = make_float4(tv[0], tv[1], tv[2], tv[3]);
  *(float4*)&T[i0] = t4;
  *(float4*)&Z1[i0] = t4;
}

// ---------------------------------------------------------------------------
// 512x512x512 fp32 matmul body (32x32 tile / block, 2x2 per thread)
// ---------------------------------------------------------------------------
__device__ __forceinline__ void mm512_body(const float* __restrict__ A,
                                           const float* __restrict__ B,
                                           float* a00, float* a01, float* a10,
                                           float* a11, int rbase, int cbase) {
  __shared__ float As[32][36];
  __shared__ float Bs[32][36];
  const int t = threadIdx.x;
  const int tx = t & 15, ty = t >> 4;
  const int sr = t >> 3, sc = (t & 7) * 4;
  float c00 = 0.f, c01 = 0.f, c10 = 0.f, c11 = 0.f;
  for (int k0 = 0; k0 < D; k0 += 32) {
    __syncthreads();
    *(float4*)&As[sr][sc] = *(const float4*)(A + (size_t)(rbase + sr) * D + k0 + sc);
    *(float4*)&Bs[sr][sc] = *(const float4*)(B + (size_t)(k0 + sr) * D + cbase + sc);
    __syncthreads();
#pragma unroll
    for (int kk = 0; kk < 32; ++kk) {
      const float av0 = As[2 * ty][kk], av1 = As[2 * ty + 1][kk];
      const float2 bv = *(const float2*)&Bs[kk][2 * tx];
      c00 = fmaf(av0, bv.x, c00);
      c01 = fmaf(av0, bv.y, c01);
      c10 = fmaf(av1, bv.x, c10);
      c11 = fmaf(av1, bv.y, c11);
    }
  }
  *a00 = c00; *a01 = c01; *a10 = c10; *a11 = c11;
}

// O = A @ B (plain store)
__global__ __launch_bounds__(256) void mmY_k(const float* __restrict__ A,
                                             const float* __restrict__ B,
                                             float* __restrict__ O) {
  const int rbase = blockIdx.y * 32, cbase = blockIdx.x * 32;
  float a00, a01, a10, a11;
  mm512_body(A, B, &a00, &a01, &a10, &a11, rbase, cbase);
  const int tx = threadIdx.x & 15, ty = threadIdx.x >> 4;
  const int r0 = rbase + 2 * ty, c0 = cbase + 2 * tx;
  O[(size_t)r0 * D + c0] = a00;
  O[(size_t)r0 * D + c0 + 1] = a01;
  O[(size_t)(r0 + 1) * D + c0] = a10;
  O[(size_t)(r0 + 1) * D + c0 + 1] = a11;
}

// T = 1.5 I - 0.5 * (Z @ Y)
__global__ __launch_bounds__(256) void mmT_k(const float* __restrict__ Zm,
                                             const float* __restrict__ Ym,
                                             float* __restrict__ T) {
  const int rbase = blockIdx.y * 32, cbase = blockIdx.x * 32;
  float a00, a01, a10, a11;
  mm512_body(Zm, Ym, &a00, &a01, &a10, &a11, rbase, cbase);
  const int tx = threadIdx.x & 15, ty = threadIdx.x >> 4;
  const int r0 = rbase + 2 * ty, c0 = cbase + 2 * tx;
  T[(size_t)r0 * D + c0] = (r0 == c0 ? 1.5f : 0.f) - 0.5f * a00;
  T[(size_t)r0 * D + c0 + 1] = (r0 == c0 + 1 ? 1.5f : 0.f) - 0.5f * a01;
  T[(size_t)(r0 + 1) * D + c0] = (r0 + 1 == c0 ? 1.5f : 0.f) - 0.5f * a10;
  T[(size_t)(r0 + 1) * D + c0 + 1] = (r0 + 1 == c0 + 1 ? 1.5f : 0.f) - 0.5f * a11;
}

// z=0: Ynew = Y @ T ; z=1: Znew = T @ Z
__global__ __launch_bounds__(256) void mmpair_k(const float* __restrict__ Y,
                                                const float* __restrict__ Z,
                                                const float* __restrict__ T,
                                                float* __restrict__ Yn,
                                                float* __restrict__ Zn) {
  const float* A = blockIdx.z ? T : Y;
  const float* B = blockIdx.z ? Z : T;
  float* O = blockIdx.z ? Zn : Yn;
  const int rbase = blockIdx.y * 32, cbase = blockIdx.x * 32;
  float a00, a01, a10, a11;
  mm512_body(A, B, &a00, &a01, &a10, &a11, rbase, cbase);
  const int tx = threadIdx.x & 15, ty = threadIdx.x >> 4;
  const int r0 = rbase + 2 * ty, c0 = cbase + 2 * tx;
  O[(size_t)r0 * D + c0] = a00;
  O[(size_t)r0 * D + c0 + 1] = a01;
  O[(size_t)(r0 + 1) * D + c0] = a10;
  O[(size_t)(r0 + 1) * D + c0 + 1] = a11;
}

// ---------------------------------------------------------------------------
// Kernel 4 (final NS iter, fused): Zfinal = T @ Z, written as pre-swizzled
// bf16 panels (BK=32 layout) scaled by 1/sqrt(s).
// panel layout: [nb(4)][ks(16 of k=32)][nl(128)][ch'(4)][e(8)] bf16 (512 KB)
// ch' = (kl>>3) ^ ((nl>>1)&3)
// ---------------------------------------------------------------------------
__global__ __launch_bounds__(256) void mmZp_k(const float* __restrict__ T,
                                              const float* __restrict__ Z,
                                              const unsigned* __restrict__ sMax,
                                              short* __restrict__ panels) {
  const int rbase = blockIdx.y * 32, cbase = blockIdx.x * 32;
  float a00, a01, a10, a11;
  mm512_body(T, Z, &a00, &a01, &a10, &a11, rbase, cbase);
  const float rs = rsqrtf(__uint_as_float(*sMax));
  const int tx = threadIdx.x & 15, ty = threadIdx.x >> 4;
  const int r0 = rbase + 2 * ty, c0 = cbase + 2 * tx;
  const float vv[2][2] = {{a00, a01}, {a10, a11}};
#pragma unroll
  for (int dr = 0; dr < 2; ++dr)
#pragma unroll
    for (int dc = 0; dc < 2; ++dc) {
      const int k = r0 + dr, n = c0 + dc;
      const int nb_ = n >> 7, nl = n & 127;
      const int ks = k >> 5, kl = k & 31;
      const int ch = (kl >> 3) ^ ((nl >> 1) & 3), e = kl & 7;
      const size_t pi = (size_t)((nb_ * 16 + ks) * 128 + nl) * 32 + ch * 8 + e;
      panels[pi] = (short)f2bf(vv[dr][dc] * rs);
    }
}

// ---------------------------------------------------------------------------
// Kernel 5: out = x @ B. grid 8192, 256 thr. BK=32, LDS 32KB (was 64KB) ->
// 4-5 blocks/CU (r10's 2 blocks/CU starved the DMA stream). 16 steps,
// 2-deep counted-vmcnt pipeline (4 issues/wave/stage -> vmcnt(4)).
// Both-sides swizzle GSW on 64B rows (conflict-free fragment reads).
// ---------------------------------------------------------------------------
__global__ __launch_bounds__(256) void gemm_k(const short* __restrict__ xb16,
                                              const short* __restrict__ panels,
                                              float* __restrict__ out) {
  __shared__ short lds[4][128 * 32];  // [0,1]=A dbuf, [2,3]=B dbuf (32 KB)

  const int hw = blockIdx.x;
  const int q = hw & 7, j = hw >> 3;
  const int ct = j & 3;
  const int rp = ((j >> 2) << 3) | q;
  const size_t rbase = (size_t)rp * 128;

  const int tid = threadIdx.x;
  const int lane = tid & 63, wave = tid >> 6;
  const int wr = wave >> 1, wc = wave & 1;
  const int l15 = lane & 15, g = lane >> 4;

  f32x4 acc[4][4];
#pragma unroll
  for (int i = 0; i < 4; ++i)
#pragma unroll
    for (int j2 = 0; j2 < 4; ++j2) acc[i][j2] = f32x4{0.f, 0.f, 0.f, 0.f};

  auto STAGE = [&](int buf, int ksv) {
    // A: 2 issues/wave of 1KB (16 rows each); src carries GSW, LDS linear
#pragma unroll
    for (int i = 0; i < 2; ++i) {
      const int rowbase = wave * 32 + i * 16;
      const int m = rowbase + (lane >> 2);
      const short* src =
          xb16 + (rbase + m) * D + ksv * 32 + GSW(m, lane & 3);
      gld_lds16(src, &lds[buf][rowbase * 32]);
    }
    // B: 2 issues/wave, linear copy of pre-swizzled 8KB panel slice
    const short* srcB = panels + ((size_t)(ct * 16 + ksv) << 12);
#pragma unroll
    for (int i = 0; i < 2; ++i)
      gld_lds16(srcB + wave * 1024 + i * 512 + lane * 8,
                &lds[2 + buf][wave * 1024 + i * 512]);
  };

  STAGE(0, 0);  // prologue: 4 DMAs/wave in flight

  for (int ks = 0; ks < 16; ++ks) {
    const int cur = ks & 1;
    if (ks < 15) {
      STAGE(cur ^ 1, ks + 1);
      asm volatile("s_waitcnt vmcnt(4)" ::: "memory");  // stage ks landed
    } else {
      asm volatile("s_waitcnt vmcnt(0)" ::: "memory");
    }
    __builtin_amdgcn_s_barrier();
    __builtin_amdgcn_sched_barrier(0);

    const short* rA = lds[cur];
    const short* rB = lds[2 + cur];
    s16x8 af[4], bfv[4];
#pragma unroll
    for (int mi = 0; mi < 4; ++mi) {
      const int m = 64 * wr + 16 * mi + l15;
      af[mi] = *(const s16x8*)(rA + m * 32 + GSW(m, g));
    }
#pragma unroll
    for (int nj = 0; nj < 4; ++nj) {
      const int n = 64 * wc + 16 * nj + l15;
      bfv[nj] = *(const s16x8*)(rB + n * 32 + GSW(n, g));
    }
#pragma unroll
    for (int mi = 0; mi < 4; ++mi)
#pragma unroll
      for (int nj = 0; nj < 4; ++nj)
        acc[mi][nj] = mfma16(af[mi], bfv[nj], acc[mi][nj]);

    asm volatile("s_waitcnt lgkmcnt(0)" ::: "memory");
    __builtin_amdgcn_s_barrier();
    __builtin_amdgcn_sched_barrier(0);
  }

  // epilogue: per-wave transpose through LDS, contiguous float4 NT stores
  float* scratch = (float*)&lds[0][0];
  const int wbase = wave * 1088;  // 16 rows x 68 floats per wave (17.4 KB)
#pragma unroll
  for (int mi = 0; mi < 4; ++mi) {
#pragma unroll
    for (int nj = 0; nj < 4; ++nj)
#pragma unroll
      for (int r = 0; r < 4; ++r)
        scratch[wbase + (4 * g + r) * 68 + 16 * nj + l15] = acc[mi][nj][r];
    __syncthreads();
#pragma unroll
    for (int i = 0; i < 4; ++i) {
      const int rl = g + 4 * i;  // 0..15
      const f32x4 v = *(const f32x4*)&scratch[wbase + rl * 68 + l15 * 4];
      const size_t row_g = rbase + 64 * wr + 16 * mi + rl;
      const int col_g = ct * 128 + 64 * wc + l15 * 4;
      __builtin_nontemporal_store(v, (f32x4*)(out + row_g * D + col_g));
    }
    __syncthreads();
  }
}

// ---------------------------------------------------------------------------
// Fallback (ws too small for xb16): A from fp32 x with f2bf, BK=32 layout.
// ---------------------------------------------------------------------------
__global__ __launch_bounds__(256) void gemm_fb_k(const float* __restrict__ x,
                                                 const short* __restrict__ panels,
                                                 float* __restrict__ out) {
  __shared__ short lds[2][128 * 32];  // [A, B] single-buffered (16 KB)

  const int hw = blockIdx.x;
  const int q = hw & 7, j = hw >> 3;
  const int ct = j & 3;
  const int rp = ((j >> 2) << 3) | q;
  const size_t rbase = (size_t)rp * 128;

  const int tid = threadIdx.x;
  const int lane = tid & 63, wave = tid >> 6;
  const int wr = wave >> 1, wc = wave & 1;
  const int l15 = lane & 15, g = lane >> 4;

  const int am = tid >> 1;            // row 0..127
  const int ak0 = (tid & 1) * 16;     // k offset 0 or 16

  f32x4 acc[4][4];
#pragma unroll
  for (int i = 0; i < 4; ++i)
#pragma unroll
    for (int j2 = 0; j2 < 4; ++j2) acc[i][j2] = f32x4{0.f, 0.f, 0.f, 0.f};

  for (int ks = 0; ks < 16; ++ks) {
    __syncthreads();
    // A: thread converts 16 k-elems of row am -> 2 swizzled 16B writes
#pragma unroll
    for (int h = 0; h < 2; ++h) {
      const float4 v =
          *(const float4*)(x + (rbase + am) * D + ks * 32 + ak0 + h * 4 + 0);
      const float4 v2 =
          *(const float4*)(x + (rbase + am) * D + ks * 32 + ak0 + h * 8 + 4);
      (void)v2;
    }
    {
      s16x8 p;
#pragma unroll
      for (int h = 0; h < 2; ++h) {
        const float4 a =
            *(const float4*)(x + (rbase + am) * D + ks * 32 + ak0 + h * 8);
        const float4 b =
            *(const float4*)(x + (rbase + am) * D + ks * 32 + ak0 + h * 8 + 4);
        p[0] = (short)f2bf(a.x); p[1] = (short)f2bf(a.y);
        p[2] = (short)f2bf(a.z); p[3] = (short)f2bf(a.w);
        p[4] = (short)f2bf(b.x); p[5] = (short)f2bf(b.y);
        p[6] = (short)f2bf(b.z); p[7] = (short)f2bf(b.w);
        const int ch = (ak0 >> 3) + h;  // 0..3
        *(s16x8*)(&lds[0][am * 32] + GSW(am, ch)) = p;
      }
    }
    // B: DMA linear copy of pre-swizzled 8KB slice
    {
      const short* srcB = panels + ((size_t)(ct * 16 + ks) << 12);
#pragma unroll
      for (int i = 0; i < 2; ++i)
        gld_lds16(srcB + wave * 1024 + i * 512 + lane * 8,
                  &lds[1][wave * 1024 + i * 512]);
    }
    __syncthreads();

    s16x8 af[4], bfv[4];
#pragma unroll
    for (int mi = 0; mi < 4; ++mi) {
      const int m = 64 * wr + 16 * mi + l15;
      af[mi] = *(const s16x8*)(&lds[0][m * 32] + GSW(m, g));
    }
#pragma unroll
    for (int nj = 0; nj < 4; ++nj) {
      const int n = 64 * wc + 16 * nj + l15;
      bfv[nj] = *(const s16x8*)(&lds[1][n * 32] + GSW(n, g));
    }
#pragma unroll
    for (int mi = 0; mi < 4; ++mi)
#pragma unroll
      for (int nj = 0; nj < 4; ++nj)
        acc[mi][nj] = mfma16(af[mi], bfv[nj], acc[mi][nj]);
  }

  __syncthreads();
  float* scratch = (float*)&lds[0][0];
  const int wbase = wave * 1088;
#pragma unroll
  for (int mi = 0; mi < 4; ++mi) {
#pragma unroll
    for (int nj = 0; nj < 4; ++nj)
#pragma unroll
      for (int r = 0; r < 4; ++r)
        scratch[wbase + (4 * g + r) * 68 + 16 * nj + l15] = acc[mi][nj][r];
    __syncthreads();
#pragma unroll
    for (int i = 0; i < 4; ++i) {
      const int rl = g + 4 * i;
      const f32x4 v = *(const f32x4*)&scratch[wbase + rl * 68 + l15 * 4];
      const size_t row_g = rbase + 64 * wr + 16 * mi + rl;
      const int col_g = ct * 128 + 64 * wc + l15 * 4;
      __builtin_nontemporal_store(v, (f32x4*)(out + row_g * D + col_g));
    }
    __syncthreads();
  }
}

// ---------------------------------------------------------------------------
extern "C" void kernel_launch(void* const* d_in, const int* in_sizes, int n_in,
                              void* d_out, int out_size, void* d_ws,
                              size_t ws_size, hipStream_t stream) {
  (void)in_sizes; (void)n_in; (void)out_size;
  const float* x = (const float*)d_in[0];
  const float* run = (const float*)d_in[1];
  float* out = (float*)d_out;
  uint8_t* ws = (uint8_t*)d_ws;

  float* Cpart = (float*)ws;                          // 8 MB (8 x 1MB)
  unsigned* sMax = (unsigned*)(ws + (8u << 20));      // 256 B slot
  float* M = (float*)(ws + (8u << 20) + 256);         // 1 MB
  float* Ya = M + 262144;
  float* Yb = Ya + 262144;
  float* Za = Yb + 262144;
  float* Zb = Za + 262144;
  float* T = Zb + 262144;
  short* panels = (short*)(T + 262144);               // 512 KB
  short* xb16 = panels + 262144;                      // 256 MB (optional)

  const size_t need =
      (size_t)((uint8_t*)xb16 - ws) + (size_t)N_ROWS * D * sizeof(short);
  const bool big = ws_size >= need;

  (void)hipMemsetAsync(Cpart, 0, (8u << 20) + 256, stream);

  covar_k<<<1280, 512, 0, stream>>>(x, Cpart, big ? xb16 : nullptr);
  prep_k<<<512, 256, 0, stream>>>(Cpart, run, M, sMax);

  // NS iter 1 (Z0 = I): T1 elementwise, Z1 = T1, Y1 = Y0 @ T1
  init2_k<<<256, 256, 0, stream>>>(M, sMax, Ya, T, Za);
  mmY_k<<<dim3(16, 16), 256, 0, stream>>>(Ya, T, Yb);

  // NS iters 2..NS_ITERS-1 (full coupled)
  float *Y = Yb, *Z = Za, *Yn = Ya, *Zn = Zb;
  for (int it = 1; it < NS_ITERS - 1; ++it) {
    mmT_k<<<dim3(16, 16), 256, 0, stream>>>(Z, Y, T);
    mmpair_k<<<dim3(16, 16, 2), 256, 0, stream>>>(Y, Z, T, Yn, Zn);
    float* t1 = Y; Y = Yn; Yn = t1;
    t1 = Z; Z = Zn; Zn = t1;
  }

  // final NS iter: only Z needed; fused panel build (BK=32 layout)
  mmT_k<<<dim3(16, 16), 256, 0, stream>>>(Z, Y, T);
  mmZp_k<<<dim3(16, 16), 256, 0, stream>>>(T, Z, sMax, panels);

  if (big)
    gemm_k<<<8192, 256, 0, stream>>>(xb16, panels, out);
  else
    gemm_fb_k<<<8192, 256, 0, stream>>>(x, panels, out);
}